// Round 18
// baseline (587.337 us; speedup 1.0000x reference)
//
#include <hip/hip_runtime.h>
#include <hip/hip_bf16.h>
#include <math.h>

// Problem constants
#define BB 4
#define SEQL 12
#define NN 1024
#define SEGL 3
#define SEGN 4
#define HID 64
#define FFD 2048
#define DKK 32
#define NHH 8
#define HDD 8
#define ZS 1048576   // floats per z stream [4,1024,4,64]

using bf16 = __hip_bfloat16;
__device__ __forceinline__ float b2f(bf16 v) { return __bfloat162float(v); }

typedef __attribute__((ext_vector_type(8))) short s8v;   // 8 bf16 (4 VGPRs)
typedef __attribute__((ext_vector_type(4))) float f4v;   // MFMA C/D
typedef __attribute__((ext_vector_type(4))) unsigned short u4v;

__device__ __forceinline__ unsigned short f2b(float f) {
  bf16 h = __float2bfloat16(f);
  unsigned short u; __builtin_memcpy(&u, &h, 2); return u;
}
__device__ __forceinline__ float us2f(unsigned short u) {
  unsigned int e = ((unsigned int)u) << 16;
  float f; __builtin_memcpy(&f, &e, 4); return f;
}

// dtype-templated loads: F=1 fp32 storage, F=0 bf16 storage
template <int F>
__device__ __forceinline__ float ldw(const void* p, long i) {
  if (F) return ((const float*)p)[i];
  return b2f(((const bf16*)p)[i]);
}
template <int F>
__device__ __forceinline__ s8v ldfrag(const void* p, long elemOff) {
  if (F) {
    const float* fp = (const float*)p + elemOff;
    f4v u = *(const f4v*)fp, v = *(const f4v*)(fp + 4);
    s8v t;
    t[0]=f2b(u[0]); t[1]=f2b(u[1]); t[2]=f2b(u[2]); t[3]=f2b(u[3]);
    t[4]=f2b(v[0]); t[5]=f2b(v[1]); t[6]=f2b(v[2]); t[7]=f2b(v[3]);
    return t;
  }
  return *(const s8v*)((const unsigned short*)p + elemOff);
}
template <int F>
__device__ __forceinline__ f4v ldb4(const void* p, long i) {  // 4 consecutive vals
  if (F) return *(const f4v*)((const float*)p + i);
  u4v u = *(const u4v*)((const unsigned short*)p + i);
  f4v r; r[0]=us2f(u[0]); r[1]=us2f(u[1]); r[2]=us2f(u[2]); r[3]=us2f(u[3]);
  return r;
}

// ---------------------------------------------------------------- zero-fill d_out (guard path)
__global__ void k_zero(unsigned short* __restrict__ o, int n) {
  int i = blockIdx.x * 256 + threadIdx.x;
  if (i < n) o[i] = 0;
}

// ---------------------------------------------------------------- detect dtype
__global__ void k_detect(const void* __restrict__ x0, int* __restrict__ flag) {
  int t = threadIdx.x;
  int bad = 0;
  const bf16* p = (const bf16*)x0;
  for (int i = t; i < 512; i += 256) {
    float a = fabsf(b2f(p[i]));
    if (!(a < 1e4f) || (a != 0.f && a < 1e-4f)) bad = 1;
  }
  __shared__ int tot;
  if (t == 0) tot = 0;
  __syncthreads();
  unsigned long long m = __ballot(bad);
  if ((t & 63) == 0) atomicAdd(&tot, __popcll(m));
  __syncthreads();
  if (t == 0) *flag = (tot > 64) ? 1 : 0;   // 1 = fp32 storage, 0 = bf16
}

// ---------------------------------------------------------------- weight convert, ALL 16 FF mats
// layout: [si 0..3][which 0..3][131072], which: 0=ff1 1=ff2 2=ga_ff1 3=ga_ff2
template <int F>
__device__ __forceinline__ void wconv_body(const void* __restrict__ w1,
    const void* __restrict__ w2, const void* __restrict__ w3,
    const void* __restrict__ w4, unsigned short* __restrict__ out) {
  int i = blockIdx.x * 256 + threadIdx.x;
  long e8 = (long)i * 8;
  int slot = (int)(e8 >> 17);       // 0..15
  int si = slot >> 2, which = slot & 3;
  long r = e8 & 131071;
  const void* src = (which == 0) ? w1 : (which == 1) ? w2 : (which == 2) ? w3 : w4;
  *(s8v*)(out + e8) = ldfrag<F>(src, (long)si*FFD*HID + r);
}
__global__ __launch_bounds__(256) void k_wconv(const void* w1, const void* w2,
    const void* w3, const void* w4, unsigned short* out,
    const int* __restrict__ flag) {
  if (*flag) wconv_body<1>(w1, w2, w3, w4, out);
  else       wconv_body<0>(w1, w2, w3, w4, out);
}

// ---------------------------------------------------------------- FF staging helpers (v11)
#define TT 64
#define FRW 64
#define HCS 74

__device__ __forceinline__ void ff_ld(const unsigned short* __restrict__ wc1,
    const unsigned short* __restrict__ wc2, int hb, int srow, int le,
    s8v* r1, s8v* r2) {
  r1[0] = *(const s8v*)(wc1 + (long)(hb + srow)*HID + le*8);
  r1[1] = *(const s8v*)(wc1 + (long)(hb + srow + 8)*HID + le*8);
  r2[0] = *(const s8v*)(wc2 + (long)srow*FFD + hb + le*8);
  r2[1] = *(const s8v*)(wc2 + (long)(srow + 8)*FFD + hb + le*8);
}
__device__ __forceinline__ void ff_wr(char* ldsbuf, int pb, int srow, int swb,
    const s8v* r1, const s8v* r2) {
  char* w1b = ldsbuf + pb*8192;
  char* w2b = ldsbuf + 16384 + pb*8192;
  *(s8v*)(w1b + srow*128 + swb) = r1[0];
  *(s8v*)(w1b + (srow + 8)*128 + swb) = r1[1];
  *(s8v*)(w2b + srow*128 + swb) = r2[0];
  *(s8v*)(w2b + (srow + 8)*128 + swb) = r2[1];
}
// one 64-h compute step: FF1 tile -> ReLU -> hcw; FF2 partial into acc
template <int F>
__device__ __forceinline__ void ff_compute(const char* ldsbuf, int pb, int hb,
    int col, int quad, int sw, const s8v* bx, unsigned short* hcw,
    const void* __restrict__ B1, long ob1, f4v* acc) {
  const char* w1b = ldsbuf + pb*8192;
  const char* w2b = ldsbuf + 16384 + pb*8192;
#pragma unroll
  for (int t = 0; t < 4; ++t) {
    int row = t*16 + col;
    s8v a10 = *(const s8v*)(w1b + row*128 + ((quad*16) ^ sw));
    s8v a11 = *(const s8v*)(w1b + row*128 + ((64 + quad*16) ^ sw));
    f4v bv = ldb4<F>(B1, ob1 + hb + t*16 + quad*4);
    f4v sv = __builtin_amdgcn_mfma_f32_16x16x32_bf16(a10, bx[0],
               (f4v){0.f,0.f,0.f,0.f}, 0, 0, 0);
    sv = __builtin_amdgcn_mfma_f32_16x16x32_bf16(a11, bx[1], sv, 0, 0, 0);
    unsigned short pk[4];
#pragma unroll
    for (int r = 0; r < 4; ++r) pk[r] = f2b(fmaxf(sv[r] + bv[r], 0.f));
    *(unsigned long long*)&hcw[col*HCS + t*16 + quad*4] =
      (unsigned long long)pk[0] | ((unsigned long long)pk[1] << 16) |
      ((unsigned long long)pk[2] << 32) | ((unsigned long long)pk[3] << 48);
  }
#pragma unroll
  for (int ks2 = 0; ks2 < 2; ++ks2) {
    s8v bh = *(const s8v*)&hcw[col*HCS + ks2*32 + quad*8];
#pragma unroll
    for (int m = 0; m < 4; ++m) {
      int r2 = m*16 + col;
      s8v a2 = *(const s8v*)(w2b + r2*128 + ((ks2*64 + quad*16) ^ sw));
      acc[m] = __builtin_amdgcn_mfma_f32_16x16x32_bf16(a2, bh, acc[m], 0, 0, 0);
    }
  }
}
// full 32-step depth-2-pipelined FF pass (acc accumulates FF2 partials)
template <int F>
__device__ __forceinline__ void ff_run(char* ldsbuf,
    const unsigned short* __restrict__ wc1, const unsigned short* __restrict__ wc2,
    const void* __restrict__ B1, long ob1, const s8v* bx, unsigned short* hcw,
    int col, int quad, int sw, int srow, int le, int swb, f4v* acc) {
  s8v c1[2], c2[2], rA1[2], rA2[2], rB1[2], rB2[2];
  ff_ld(wc1, wc2, 0, srow, le, c1, c2);
  ff_wr(ldsbuf, 0, srow, swb, c1, c2);
  ff_ld(wc1, wc2, 64, srow, le, rA1, rA2);
  ff_ld(wc1, wc2, 128, srow, le, rB1, rB2);
  __syncthreads();
  for (int c = 0; c < 32; c += 2) {
    ff_compute<F>(ldsbuf, 0, c*64, col, quad, sw, bx, hcw, B1, ob1, acc);
    ff_wr(ldsbuf, 1, srow, swb, rA1, rA2);
    if (c + 3 < 32) ff_ld(wc1, wc2, (c+3)*64, srow, le, rA1, rA2);
    __syncthreads();
    ff_compute<F>(ldsbuf, 1, (c+1)*64, col, quad, sw, bx, hcw, B1, ob1, acc);
    if (c + 2 < 32) ff_wr(ldsbuf, 0, srow, swb, rB1, rB2);
    if (c + 4 < 32) ff_ld(wc1, wc2, (c+4)*64, srow, le, rB1, rB2);
    __syncthreads();
  }
}

// ---------------------------------------------------------------- FUSED {patch | gaFF(prev)} + temporal attn + FF + graph qkv (k_tff)
template <int F>
__device__ __forceinline__ void tff_body(float* __restrict__ zb,
    const void* __restrict__ xt, const void* __restrict__ xu,
    const void* __restrict__ pw, const void* __restrict__ pbp,
    const void* __restrict__ W, const void* __restrict__ bq,
    const void* __restrict__ WO, const void* __restrict__ bo,
    const void* __restrict__ g1, const void* __restrict__ b1,
    const unsigned short* __restrict__ wcw, int li,
    const void* __restrict__ B1, const void* __restrict__ B2,
    const void* __restrict__ G, const void* __restrict__ Bt,
    const void* __restrict__ pgf1b, const void* __restrict__ pgf2b,
    const void* __restrict__ pgl2g, const void* __restrict__ pgl2b,
    const void* __restrict__ gwq, const void* __restrict__ gwk,
    const void* __restrict__ gwv,
    unsigned short* __restrict__ qo, unsigned short* __restrict__ ko,
    unsigned short* __restrict__ vto,
    char* lds) {
  int s = blockIdx.x >> 8, blk = blockIdx.x & 255;
  long si = s*2 + li;
  float* z = zb + (long)s*ZS;
  long oW = si*3*HID*HID, obq = si*3*HID, oWO = si*HID*HID, obo = si*HID;
  long og1 = si*HID, ob1 = si*HID;
  const unsigned short* wc1 = wcw + (si*4 + 0)*131072;
  const unsigned short* wc2 = wcw + (si*4 + 1)*131072;
  long fob1 = si*FFD, fob2 = si*HID, fog = si*HID, fobt = si*HID;
  unsigned short (*qkvs)[200] = (unsigned short(*)[200])lds;        // 25600 B
  unsigned short (*ao)[72]    = (unsigned short(*)[72])(lds + 25600); // 9216 B
  float (*yb)[68]             = (float(*)[68])(lds + 34816);          // 17408 B
  int tid = threadIdx.x;
  int w = tid >> 6, lane = tid & 63;
  int col = lane & 15, quad = lane >> 4;
  long r0 = (long)blk * TT;
  float* stash = (float*)(lds + 59648);             // [64][68] block-wide
  float* stashW = stash + w*16*68;                  // wave's rows
  unsigned short* hcw = (unsigned short*)(lds + 32768 + w*2368);  // [16][74]
  float* red = (float*)(lds + 42240 + w*4352);                    // [16][68]
  int lr = lane >> 3, le = lane & 7;
  int srow = w*16 + lr;
  int swb = ((le ^ lr) << 4);
  const int sw = (col & 7) << 4;

  if (li == 0) {
    // ================= phase 0: patch embed -> stash =================
    const void* x = s ? xu : xt;
    long opw = (long)s*HID*SEGL, opb = (long)s*HID;
    float dv = expf((float)(2*(lane >> 1)) * (-logf(10000.f) / (float)HID));
    float pe[4];
#pragma unroll
    for (int g = 0; g < 4; ++g) {
      float ang = (float)g * dv;
      pe[g] = (lane & 1) ? cosf(ang) : sinf(ang);
    }
    float pbv = ldw<F>(pbp, opb + lane);
    float pwv[3];
#pragma unroll
    for (int l = 0; l < 3; ++l) pwv[l] = ldw<F>(pw, opw + lane*3 + l);
#pragma unroll
    for (int rr = 0; rr < 16; ++rr) {
      long tok = r0 + w*16 + rr;
      int b_ = (int)(tok >> 12);
      int n_ = (int)((tok >> 2) & 1023);
      int g_ = (int)(tok & 3);
      float a = pbv;
#pragma unroll
      for (int l = 0; l < 3; ++l)
        a += ldw<F>(x, (long)(b_*SEQL + g_*SEGL + l)*NN + n_) * pwv[l];
      stashW[rr*68 + lane] = a + pe[g_];
    }
    __syncthreads();
  } else {
    // ================= phase -1: gaFF of layer 0 -> stash =================
    long sip = s*2;                    // prev layer (li==0) slot
    const unsigned short* pw1 = wcw + (sip*4 + 2)*131072;
    const unsigned short* pw2 = wcw + (sip*4 + 3)*131072;
    long pob1 = sip*FFD, pob2 = sip*HID, pog = sip*HID, pobt = sip*HID;
    s8v bxp[2];
    {
      const float* xr = z + (r0 + w*16 + col) * HID;
#pragma unroll
      for (int ks = 0; ks < 2; ++ks) {
        const float* p = xr + ks*32 + quad*8;
        f4v u = *(const f4v*)p, v = *(const f4v*)(p + 4);
        s8v t;
        t[0]=f2b(u[0]); t[1]=f2b(u[1]); t[2]=f2b(u[2]); t[3]=f2b(u[3]);
        t[4]=f2b(v[0]); t[5]=f2b(v[1]); t[6]=f2b(v[2]); t[7]=f2b(v[3]);
        bxp[ks] = t;
      }
    }
    f4v accp[4];
#pragma unroll
    for (int m = 0; m < 4; ++m) accp[m] = (f4v){0.f,0.f,0.f,0.f};
    ff_run<F>(lds, pw1, pw2, pgf1b, pob1, bxp, hcw, col, quad, sw, srow, le, swb, accp);
#pragma unroll
    for (int m = 0; m < 4; ++m)
      *(f4v*)&red[col*68 + m*16 + quad*4] = accp[m];
    float pgg = ldw<F>(pgl2g, pog + lane), pbb = ldw<F>(pgl2b, pobt + lane);
    float pb2 = ldw<F>(pgf2b, pob2 + lane);
#pragma unroll
    for (int rr = 0; rr < 16; ++rr) {
      long grow = r0 + w*16 + rr;
      float val = red[rr*68 + lane] + pb2 + z[grow*HID + lane];
      float sm = val;
#pragma unroll
      for (int off = 32; off; off >>= 1) sm += __shfl_xor(sm, off);
      float m = sm * (1.f/HID);
      float d = val - m;
      float sq = d*d;
#pragma unroll
      for (int off = 32; off; off >>= 1) sq += __shfl_xor(sq, off);
      float rv = rsqrtf(sq*(1.f/HID) + 1e-5f);
      stashW[rr*68 + lane] = d*rv*pgg + pbb;
    }
    __syncthreads();
  }

  // ================= phase 1: temporal attention (input from stash) =================
  s8v bx[4][2];
#pragma unroll
  for (int mt = 0; mt < 4; ++mt) {
    const float* xr = &stash[(mt*16 + col)*68];
#pragma unroll
    for (int ks = 0; ks < 2; ++ks) {
      const float* p = xr + ks*32 + quad*8;
      f4v u = *(const f4v*)p, v = *(const f4v*)(p + 4);
      s8v t;
      t[0]=f2b(u[0]); t[1]=f2b(u[1]); t[2]=f2b(u[2]); t[3]=f2b(u[3]);
      t[4]=f2b(v[0]); t[5]=f2b(v[1]); t[6]=f2b(v[2]); t[7]=f2b(v[3]);
      bx[mt][ks] = t;
    }
  }
#pragma unroll
  for (int nt = 0; nt < 3; ++nt) {
    int cbase = (w*3 + nt) * 16;
    s8v aw[2];
#pragma unroll
    for (int ks = 0; ks < 2; ++ks)
      aw[ks] = ldfrag<F>(W, oW + (long)(cbase + col)*HID + ks*32 + quad*8);
    f4v bv = ldb4<F>(bq, obq + cbase + quad*4);
#pragma unroll
    for (int mt = 0; mt < 4; ++mt) {
      f4v sv = (f4v){0.f,0.f,0.f,0.f};
#pragma unroll
      for (int ks = 0; ks < 2; ++ks)
        sv = __builtin_amdgcn_mfma_f32_16x16x32_bf16(aw[ks], bx[mt][ks], sv, 0, 0, 0);
      unsigned short pk[4];
#pragma unroll
      for (int r = 0; r < 4; ++r) pk[r] = f2b(sv[r] + bv[r]);
      *(unsigned long long*)&qkvs[mt*16 + col][cbase + quad*4] =
        (unsigned long long)pk[0] | ((unsigned long long)pk[1] << 16) |
        ((unsigned long long)pk[2] << 32) | ((unsigned long long)pk[3] << 48);
    }
  }
  __syncthreads();
  if (tid < 128) {
    int gi = tid >> 3, hd = tid & 7;
    int tl = gi * 4;
    float qv[4][8], kv[4][8], vv[4][8];
#pragma unroll
    for (int t4 = 0; t4 < 4; ++t4) {
      s8v qq = *(const s8v*)&qkvs[tl + t4][hd*8];
      s8v kk = *(const s8v*)&qkvs[tl + t4][64 + hd*8];
      s8v vq = *(const s8v*)&qkvs[tl + t4][128 + hd*8];
#pragma unroll
      for (int e = 0; e < 8; ++e) {
        qv[t4][e] = us2f((unsigned short)qq[e]);
        kv[t4][e] = us2f((unsigned short)kk[e]);
        vv[t4][e] = us2f((unsigned short)vq[e]);
      }
    }
    const float sc8 = 0.3535533905932738f;   // 1/sqrt(8)
#pragma unroll
    for (int qt = 0; qt < 4; ++qt) {
      float sc[4]; float mx = -1e30f;
#pragma unroll
      for (int kt = 0; kt < 4; ++kt) {
        float d = 0;
#pragma unroll
        for (int e = 0; e < 8; ++e) d += qv[qt][e]*kv[kt][e];
        sc[kt] = d*sc8; mx = fmaxf(mx, sc[kt]);
      }
      float se = 0;
#pragma unroll
      for (int kt = 0; kt < 4; ++kt) { sc[kt] = expf(sc[kt]-mx); se += sc[kt]; }
      float inv = 1.f/se;
      s8v outp;
#pragma unroll
      for (int e = 0; e < 8; ++e) {
        float o = 0;
#pragma unroll
        for (int kt = 0; kt < 4; ++kt) o += sc[kt]*vv[kt][e];
        outp[e] = (short)f2b(o*inv);
      }
      *(s8v*)&ao[tl + qt][hd*8] = outp;
    }
  }
  __syncthreads();
  s8v awo[2];
#pragma unroll
  for (int ks = 0; ks < 2; ++ks)
    awo[ks] = ldfrag<F>(WO, oWO + (long)(w*16 + col)*HID + ks*32 + quad*8);
  f4v bov = ldb4<F>(bo, obo + w*16 + quad*4);
#pragma unroll
  for (int mt = 0; mt < 4; ++mt) {
    f4v ov = (f4v){0.f,0.f,0.f,0.f};
#pragma unroll
    for (int ks = 0; ks < 2; ++ks) {
      s8v bao = *(const s8v*)&ao[mt*16 + col][ks*32 + quad*8];
      ov = __builtin_amdgcn_mfma_f32_16x16x32_bf16(awo[ks], bao, ov, 0, 0, 0);
    }
    f4v yv;
#pragma unroll
    for (int r = 0; r < 4; ++r) yv[r] = ov[r] + bov[r];
    *(f4v*)&yb[mt*16 + col][w*16 + quad*4] = yv;
  }
  __syncthreads();
  {
    float gg = ldw<F>(g1, og1 + lane), bb2 = ldw<F>(b1, ob1 + lane);
#pragma unroll
    for (int rr = 0; rr < 16; ++rr) {
      int row = w*16 + rr;
      float val = yb[row][lane] + stashW[rr*68 + lane];
      float sm = val;
#pragma unroll
      for (int off = 32; off; off >>= 1) sm += __shfl_xor(sm, off);
      float m = sm*(1.f/HID);
      float d = val - m, sq = d*d;
#pragma unroll
      for (int off = 32; off; off >>= 1) sq += __shfl_xor(sq, off);
      float rv = rsqrtf(sq*(1.f/HID) + 1e-5f);
      stashW[rr*68 + lane] = d*rv*gg + bb2;     // LN1 -> stash (in-place safe)
    }
  }
  __syncthreads();   // attn LDS dead; FF regions may now be written

  // ================= phase 2: FF (depth-2 pipeline) =================
  s8v bx2[2];
#pragma unroll
  for (int ks = 0; ks < 2; ++ks) {
    const float* p = &stashW[col*68 + ks*32 + quad*8];
    f4v u = *(const f4v*)p, v = *(const f4v*)(p + 4);
    s8v t;
    t[0]=f2b(u[0]); t[1]=f2b(u[1]); t[2]=f2b(u[2]); t[3]=f2b(u[3]);
    t[4]=f2b(v[0]); t[5]=f2b(v[1]); t[6]=f2b(v[2]); t[7]=f2b(v[3]);
    bx2[ks] = t;
  }

  f4v acc[4];
#pragma unroll
  for (int m = 0; m < 4; ++m) acc[m] = (f4v){0.f,0.f,0.f,0.f};
  ff_run<F>(lds, wc1, wc2, B1, fob1, bx2, hcw, col, quad, sw, srow, le, swb, acc);

#pragma unroll
  for (int m = 0; m < 4; ++m)
    *(f4v*)&red[col*68 + m*16 + quad*4] = acc[m];
  float* finb = (float*)lds;     // [64][68], overlays wdbuf (dead after loop)
  {
    float fgg = ldw<F>(G, fog + lane), fbbt = ldw<F>(Bt, fobt + lane);
    float b2v = ldw<F>(B2, fob2 + lane);
#pragma unroll
    for (int rr = 0; rr < 16; ++rr) {
      long grow = r0 + w*16 + rr;
      float val = red[rr*68 + lane] + b2v + stashW[rr*68 + lane];
      float sm = val;
#pragma unroll
      for (int off = 32; off; off >>= 1) sm += __shfl_xor(sm, off);
      float m = sm * (1.f/HID);
      float d = val - m;
      float sq = d*d;
#pragma unroll
      for (int off = 32; off; off >>= 1) sq += __shfl_xor(sq, off);
      float rv = rsqrtf(sq*(1.f/HID) + 1e-5f);
      float fin = d*rv*fgg + fbbt;
      z[grow*HID + lane] = fin;
      finb[(w*16 + rr)*68 + lane] = fin;
    }
  }
  __syncthreads();   // finb visible block-wide

  // ================= phase 3: fused graph qkv =================
  long oq = si*DKK*HID, okk = si*DKK*HID, ovv = si*HID*HID;
  s8v bx3[4][2];
#pragma unroll
  for (int rt = 0; rt < 4; ++rt)
#pragma unroll
    for (int ks = 0; ks < 2; ++ks) {
      const float* p = &finb[(rt*16 + col)*68 + ks*32 + quad*8];
      f4v u = *(const f4v*)p, v = *(const f4v*)(p + 4);
      s8v t;
      t[0]=f2b(u[0]); t[1]=f2b(u[1]); t[2]=f2b(u[2]); t[3]=f2b(u[3]);
      t[4]=f2b(v[0]); t[5]=f2b(v[1]); t[6]=f2b(v[2]); t[7]=f2b(v[3]);
      bx3[rt][ks] = t;
    }
#pragma unroll
  for (int tt = 0; tt < 2; ++tt) {
    int ct = w*2 + tt;                        // wave-uniform
    const void* wp; long wo; int co; int kind; // 0=q,1=k,2=v
    if (ct < 2)      { wp = gwq; wo = oq;  co = ct*16;      kind = 0; }
    else if (ct < 4) { wp = gwk; wo = okk; co = (ct-2)*16;  kind = 1; }
    else             { wp = gwv; wo = ovv; co = (ct-4)*16;  kind = 2; }
    s8v aw[2];
#pragma unroll
    for (int ks = 0; ks < 2; ++ks)
      aw[ks] = ldfrag<F>(wp, wo + (long)(co + col)*HID + ks*32 + quad*8);
#pragma unroll
    for (int rt = 0; rt < 4; ++rt) {
      f4v sv = (f4v){0.f,0.f,0.f,0.f};
#pragma unroll
      for (int ks = 0; ks < 2; ++ks)
        sv = __builtin_amdgcn_mfma_f32_16x16x32_bf16(aw[ks], bx3[rt][ks], sv, 0, 0, 0);
      long tok2 = r0 + rt*16 + col;
      int b_ = (int)(tok2 >> 12);
      int n_ = (int)((tok2 >> 2) & 1023);
      int g_ = (int)(tok2 & 3);
      int sgl = s*16 + b_*4 + g_;
      if (kind == 2) {
        long vbase = (long)sgl*HID*NN;
#pragma unroll
        for (int r = 0; r < 4; ++r)
          vto[vbase + (long)(co + quad*4 + r)*NN + n_] = f2b(sv[r]);
      } else {
        long row = (long)sgl*NN + n_;
        unsigned short pk[4];
#pragma unroll
        for (int r = 0; r < 4; ++r) pk[r] = f2b(sv[r]);
        unsigned short* dst = kind ? ko : qo;
        *(unsigned long long*)&dst[row*DKK + co + quad*4] =
          (unsigned long long)pk[0] | ((unsigned long long)pk[1] << 16) |
          ((unsigned long long)pk[2] << 32) | ((unsigned long long)pk[3] << 48);
      }
    }
  }
}
__global__ __launch_bounds__(256) void k_tff(float* __restrict__ z,
    const void* xt, const void* xu, const void* pw, const void* pbp,
    const void* W, const void* bqkv, const void* WO, const void* bo,
    const void* g1, const void* b1,
    const unsigned short* __restrict__ wcw, int li,
    const void* B1, const void* B2, const void* G, const void* Bt,
    const void* pgf1b, const void* pgf2b, const void* pgl2g, const void* pgl2b,
    const void* gwq, const void* gwk, const void* gwv,
    unsigned short* qo, unsigned short* ko, unsigned short* vto,
    const int* __restrict__ flag) {
  __shared__ __attribute__((aligned(16))) char lds[77056];
  if (*flag) tff_body<1>(z, xt, xu, pw, pbp, W, bqkv, WO, bo, g1, b1, wcw, li,
                         B1, B2, G, Bt, pgf1b, pgf2b, pgl2g, pgl2b,
                         gwq, gwk, gwv, qo, ko, vto, lds);
  else       tff_body<0>(z, xt, xu, pw, pbp, W, bqkv, WO, bo, g1, b1, wcw, li,
                         B1, B2, G, Bt, pgf1b, pgf2b, pgl2g, pgl2b,
                         gwq, gwk, gwv, qo, ko, vto, lds);
}

// ---------------------------------------------------------------- FUSED graph attention + gaFF + pool (k_gaf, layer 1)
// Block = 64 tokens (16 nodes x 4 segments) of one (s,b). 256 thr, 4 waves.
// Phase A: graph attention; wave w owns segment g=w (16 queries = nodes
// n0..n0+15, full 1024-key loop, per-wave softmax-sum normalize -> no
// cross-wave merge), LN + residual -> stash. Phase B: gaFF via ff_run on the
// stash + LN2 + fused segment-pool -> enc. Replaces gattn(1) + final ffmfma.
// LDS: A {pl@0 4x4736=18944, ob@18944 4x4352, lbw@36352 4x64};
// B {wdbuf@0 32768, hcw@32768 4x2368, red@0 overlay}; stash@42240 17408.
// Total 59648 -> 2 blocks/CU.
template <int F>
__device__ __forceinline__ void gaf_body(float* __restrict__ zb,
    const unsigned short* __restrict__ qb, const unsigned short* __restrict__ kb,
    const unsigned short* __restrict__ vtb,
    const void* __restrict__ g1, const void* __restrict__ b1,
    const unsigned short* __restrict__ wcw,
    const void* __restrict__ B1, const void* __restrict__ B2,
    const void* __restrict__ G, const void* __restrict__ Bt,
    float* __restrict__ enc, char* lds) {
  int s = blockIdx.x >> 8, blk = blockIdx.x & 255;
  long si = s*2 + 1;
  float* z = zb + (long)s*ZS;
  long r0 = (long)blk * TT;
  int b_ = blk >> 6;
  int n0 = (blk & 63) * 16;
  int tid = threadIdx.x;
  int w = tid >> 6, lane = tid & 63;
  int col = lane & 15, quad = lane >> 4;
  unsigned short (*plw)[16][74] = (unsigned short(*)[16][74])(lds + w*4736);
  float* obw = (float*)(lds + 18944 + w*4352);      // [16][68]
  float* lbw = (float*)(lds + 36352 + w*64);        // [16]
  float* stash = (float*)(lds + 42240);             // [64][68]
  float* stashW = stash + w*16*68;
  unsigned short* hcw = (unsigned short*)(lds + 32768 + w*2368);
  float* red = (float*)(lds + w*4352);              // overlay wdbuf (tail)
  long og1 = si*HID, obn1 = si*HID;

  // ================= phase A: graph attention (wave w = segment g) ======
  long sgw = (long)(s*16 + b_*4 + w);
  long gbaseW = sgw * NN;
  const unsigned short* vrow = vtb + sgw*(long)HID*NN;
  s8v aq = *(const s8v*)(qb + (gbaseW + n0 + col)*DKK + quad*8);
  f4v acc[4];
#pragma unroll
  for (int t = 0; t < 4; ++t) acc[t] = (f4v){0.f,0.f,0.f,0.f};
  float psum[4] = {0.f,0.f,0.f,0.f};
  const float rs = 0.17677669529663687f;   // 1/sqrt(32)

#pragma unroll 2
  for (int it = 0; it < 16; ++it) {
    int c0 = it*64;
    int pb = it & 1;
    f4v s4[4];
#pragma unroll
    for (int nt = 0; nt < 4; ++nt) {
      s8v bk = *(const s8v*)(kb + (gbaseW + c0 + nt*16 + col)*DKK + quad*8);
      s4[nt] = __builtin_amdgcn_mfma_f32_16x16x32_bf16(aq, bk,
                (f4v){0.f,0.f,0.f,0.f}, 0, 0, 0);
    }
#pragma unroll
    for (int r = 0; r < 4; ++r) {
      float p0 = expf(s4[0][r]*rs), p1 = expf(s4[1][r]*rs);
      float p2 = expf(s4[2][r]*rs), p3 = expf(s4[3][r]*rs);
      psum[r] += (p0 + p1) + (p2 + p3);
      int row = quad*4 + r;
      plw[pb][row][col]      = f2b(p0);
      plw[pb][row][16 + col] = f2b(p1);
      plw[pb][row][32 + col] = f2b(p2);
      plw[pb][row][48 + col] = f2b(p3);
    }
#pragma unroll
    for (int ks = 0; ks < 2; ++ks) {
      s8v ap = *(const s8v*)&plw[pb][col][ks*32 + quad*8];
#pragma unroll
      for (int nt = 0; nt < 4; ++nt) {
        s8v bv = *(const s8v*)(vrow + (long)(nt*16 + col)*NN + c0 + ks*32 + quad*8);
        acc[nt] = __builtin_amdgcn_mfma_f32_16x16x32_bf16(ap, bv, acc[nt], 0, 0, 0);
      }
    }
  }

#pragma unroll
  for (int r = 0; r < 4; ++r) {
    float v = psum[r];
#pragma unroll
    for (int off = 1; off < 16; off <<= 1) v += __shfl_xor(v, off);
    psum[r] = v;
  }
  if (col == 0) {
#pragma unroll
    for (int r = 0; r < 4; ++r) lbw[quad*4 + r] = psum[r];
  }
#pragma unroll
  for (int t = 0; t < 4; ++t)
#pragma unroll
    for (int r = 0; r < 4; ++r)
      obw[(quad*4 + r)*68 + t*16 + col] = acc[t][r];
  // wave-private LDS: in-wave ds ordering, no barrier needed
  {
    float gg = ldw<F>(g1, og1 + lane), bb = ldw<F>(b1, obn1 + lane);
#pragma unroll
    for (int rr = 0; rr < 16; ++rr) {
      float val = obw[rr*68 + lane] / lbw[rr];
      float sm = val;
#pragma unroll
      for (int off = 32; off; off >>= 1) sm += __shfl_xor(sm, off);
      float m = sm*(1.f/HID);
      float d = val - m, sq = d*d;
#pragma unroll
      for (int off = 32; off; off >>= 1) sq += __shfl_xor(sq, off);
      float rv = rsqrtf(sq*(1.f/HID) + 1e-5f);
      long tok = r0 + rr*4 + w;          // node n0+rr, segment w
      stash[(rr*4 + w)*68 + lane] = d*rv*gg + bb + z[tok*HID + lane];
    }
  }
  __syncthreads();   // attention LDS dead; stash complete block-wide

  // ================= phase B: gaFF + LN2 + pool =================
  const unsigned short* wc1 = wcw + (si*4 + 2)*131072;
  const unsigned short* wc2 = wcw + (si*4 + 3)*131072;
  long fob1 = si*FFD, fob2 = si*HID, fog = si*HID, fobt = si*HID;
  int lr = lane >> 3, le = lane & 7;
  int srow = w*16 + lr;
  int swb = ((le ^ lr) << 4);
  const int sw = (col & 7) << 4;

  s8v bx2[2];
#pragma unroll
  for (int ks = 0; ks < 2; ++ks) {
    const float* p = &stashW[col*68 + ks*32 + quad*8];
    f4v u = *(const f4v*)p, v = *(const f4v*)(p + 4);
    s8v t;
    t[0]=f2b(u[0]); t[1]=f2b(u[1]); t[2]=f2b(u[2]); t[3]=f2b(u[3]);
    t[4]=f2b(v[0]); t[5]=f2b(v[1]); t[6]=f2b(v[2]); t[7]=f2b(v[3]);
    bx2[ks] = t;
  }

  f4v acf[4];
#pragma unroll
  for (int m = 0; m < 4; ++m) acf[m] = (f4v){0.f,0.f,0.f,0.f};
  ff_run<F>(lds, wc1, wc2, B1, fob1, bx2, hcw, col, quad, sw, srow, le, swb, acf);

#pragma unroll
  for (int m = 0; m < 4; ++m)
    *(f4v*)&red[col*68 + m*16 + quad*4] = acf[m];
  float gg2 = ldw<F>(G, fog + lane), bbt2 = ldw<F>(Bt, fobt + lane);
  float b2v = ldw<F>(B2, fob2 + lane);
  float pacc[4] = {0.f,0.f,0.f,0.f};
#pragma unroll
  for (int rr = 0; rr < 16; ++rr) {
    float val = red[rr*68 + lane] + b2v + stashW[rr*68 + lane];
    float sm = val;
#pragma unroll
    for (int off = 32; off; off >>= 1) sm += __shfl_xor(sm, off);
    float m = sm * (1.f/HID);
    float d = val - m;
    float sq = d*d;
#pragma unroll
    for (int off = 32; off; off >>= 1) sq += __shfl_xor(sq, off);
    float rv = rsqrtf(sq*(1.f/HID) + 1e-5f);
    pacc[rr >> 2] += d*rv*gg2 + bbt2;
  }
#pragma unroll
  for (int j = 0; j < 4; ++j) {
    long tok = r0 + w*16 + j*4;
    enc[(tok >> 2)*(2*HID) + s*HID + lane] = pacc[j]*0.25f;
  }
}
__global__ __launch_bounds__(256) void k_gaf(float* __restrict__ z,
    const unsigned short* __restrict__ qb, const unsigned short* __restrict__ kb,
    const unsigned short* __restrict__ vtb,
    const void* g1, const void* b1,
    const unsigned short* __restrict__ wcw,
    const void* B1, const void* B2, const void* G, const void* Bt,
    float* enc, const int* __restrict__ flag) {
  __shared__ __attribute__((aligned(16))) char lds[59648];
  if (*flag) gaf_body<1>(z, qb, kb, vtb, g1, b1, wcw, B1, B2, G, Bt, enc, lds);
  else       gaf_body<0>(z, qb, kb, vtb, g1, b1, wcw, B1, B2, G, Bt, enc, lds);
}

// ---------------------------------------------------------------- graph attention (dual-s, 4-way key split)
// 1024 blocks: 32 queries/block, 4-way key split (kh=w&3, 256 keys each),
// 4-wave merge in LDS (no max state -> partial accs and sums just add).
__global__ __launch_bounds__(512) void k_gattn(float* __restrict__ zb,
    const unsigned short* __restrict__ qb, const unsigned short* __restrict__ kb,
    const unsigned short* __restrict__ vtb,
    const void* __restrict__ g1, const void* __restrict__ b1, int li,
    const int* __restrict__ flag) {
  int f = *flag;
  __shared__ unsigned short pl[2][8][16][74];  // ping-pong, wave-private, 74-pad
  __shared__ float accb[8][16][66];
  __shared__ float lb[8][16];
  int tid = threadIdx.x;
  int w = tid >> 6, lane = tid & 63;
  int col = lane & 15, quad = lane >> 4;
  int qt = w >> 2, kh = w & 3;
  int sg = blockIdx.x >> 5;              // 0..31
  int s = sg >> 4, bg = sg & 15;
  int n0 = (blockIdx.x & 31) * 32;
  long si = s*2 + li;
  float* z = zb + (long)s*ZS;
  long og1 = si*HID, ob1 = si*HID;
  long gbase = (long)sg * NN;
  const unsigned short* vrow = vtb + (long)sg*HID*NN;

  s8v aq = *(const s8v*)(qb + (gbase + n0 + qt*16 + col)*DKK + quad*8);

  f4v acc[4];
#pragma unroll
  for (int t = 0; t < 4; ++t) acc[t] = (f4v){0.f,0.f,0.f,0.f};
  float psum[4] = {0.f,0.f,0.f,0.f};
  const float rs = 0.17677669529663687f;   // 1/sqrt(32)
  const int cbeg = kh * 256;

#pragma unroll 2
  for (int it = 0; it < 4; ++it) {
    int c0 = cbeg + it*64;
    int pb = it & 1;
    f4v s4[4];
#pragma unroll
    for (int nt = 0; nt < 4; ++nt) {
      s8v bk = *(const s8v*)(kb + (gbase + c0 + nt*16 + col)*DKK + quad*8);
      s4[nt] = __builtin_amdgcn_mfma_f32_16x16x32_bf16(aq, bk,
                (f4v){0.f,0.f,0.f,0.f}, 0, 0, 0);
    }
#pragma unroll
    for (int r = 0; r < 4; ++r) {
      float p0 = expf(s4[0][r]*rs), p1 = expf(s4[1][r]*rs);
      float p2 = expf(s4[2][r]*rs), p3 = expf(s4[3][r]*rs);
      psum[r] += (p0 + p1) + (p2 + p3);
      int row = quad*4 + r;
      pl[pb][w][row][col]      = f2b(p0);
      pl[pb][w][row][16 + col] = f2b(p1);
      pl[pb][w][row][32 + col] = f2b(p2);
      pl[pb][w][row][48 + col] = f2b(p3);
    }
#pragma unroll
    for (int ks = 0; ks < 2; ++ks) {
      s8v ap = *(const s8v*)&pl[pb][w][col][ks*32 + quad*8];
#pragma unroll
      for (int nt = 0; nt < 4; ++nt) {
        s8v bv = *(const s8v*)(vrow + (long)(nt*16 + col)*NN + c0 + ks*32 + quad*8);
        acc[nt] = __builtin_amdgcn_mfma_f32_16x16x32_bf16(ap, bv, acc[nt], 0, 0, 0);
      }
    }
  }

#pragma unroll
  for (int r = 0; r < 4; ++r) {
    float v = psum[r];
#pragma unroll
    for (int off = 1; off < 16; off <<= 1) v += __shfl_xor(v, off);
    psum[r] = v;
  }
#pragma unroll
  for (int t = 0; t < 4; ++t)
#pragma unroll
    for (int r = 0; r < 4; ++r)
      accb[w][quad*4 + r][t*16 + col] = acc[t][r];
  if (col == 0) {
#pragma unroll
    for (int r = 0; r < 4; ++r) lb[w][quad*4 + r] = psum[r];
  }
  __syncthreads();

  int b = bg >> 2, g = bg & 3;
  float gg = f ? ((const float*)g1)[og1 + lane] : b2f(((const bf16*)g1)[og1 + lane]);
  float bb = f ? ((const float*)b1)[ob1 + lane] : b2f(((const bf16*)b1)[ob1 + lane]);
#pragma unroll
  for (int rr = 0; rr < 4; ++rr) {
    int rl = w*4 + rr;                 // 0..31
    int qtt = rl >> 4, lrr = rl & 15;
    float a = accb[4*qtt][lrr][lane] + accb[4*qtt + 1][lrr][lane]
            + accb[4*qtt + 2][lrr][lane] + accb[4*qtt + 3][lrr][lane];
    float l = lb[4*qtt][lrr] + lb[4*qtt + 1][lrr]
            + lb[4*qtt + 2][lrr] + lb[4*qtt + 3][lrr];
    float val = a / l;
    float s2 = val;
#pragma unroll
    for (int off = 32; off; off >>= 1) s2 += __shfl_xor(s2, off);
    float m = s2*(1.f/HID);
    float d = val - m, sq = d*d;
#pragma unroll
    for (int off = 32; off; off >>= 1) sq += __shfl_xor(sq, off);
    float r = rsqrtf(sq*(1.f/HID) + 1e-5f);
    float* zp = z + ((long)(b*NN + n0 + rl)*SEGN + g)*HID;
    zp[lane] = d*r*gg + bb + zp[lane];   // LN(att) + x
  }
}

// ---------------------------------------------------------------- final qkv proj (in_dim=128)
// v emitted as bf16 V^T: vt[b][dim 0..63][key 0..1023]
template <int F>
__device__ __forceinline__ void fqkv_body(const float* __restrict__ enc,
    const void* __restrict__ wq, const void* __restrict__ wk,
    const void* __restrict__ wv,
    unsigned short* __restrict__ q, unsigned short* __restrict__ k,
    unsigned short* __restrict__ vt, float* xs) {
  long r = blockIdx.x;
  int t = threadIdx.x;
  xs[t] = enc[r*128 + t];
  __syncthreads();
  if (t < 32) {
    long wr = (long)t*128; float a = 0;
    for (int e = 0; e < 128; ++e) a += xs[e]*ldw<F>(wq, wr + e);
    q[r*DKK + t] = f2b(a);
  } else if (t < 64) {
    long wr = (long)(t-32)*128; float a = 0;
    for (int e = 0; e < 128; ++e) a += xs[e]*ldw<F>(wk, wr + e);
    k[r*DKK + (t-32)] = f2b(a);
  } else {
    long wr = (long)(t-64)*128; float a = 0;
    for (int e = 0; e < 128; ++e) a += xs[e]*ldw<F>(wv, wr + e);
    vt[((r >> 10)*HID + (t-64))*NN + (r & 1023)] = f2b(a);
  }
}
__global__ __launch_bounds__(128) void k_fqkv(const float* __restrict__ enc,
    const void* wq, const void* wk, const void* wv,
    unsigned short* q, unsigned short* k, unsigned short* vt,
    const int* __restrict__ flag) {
  __shared__ float xs[2*HID];
  if (*flag) fqkv_body<1>(enc, wq, wk, wv, q, k, vt, xs);
  else       fqkv_body<0>(enc, wq, wk, wv, q, k, vt, xs);
}

// ---------------------------------------------------------------- final attention -> d_out
// 128 blocks (BB*32): 32 queries/block, 4-way key split, 4-wave merge.
__global__ __launch_bounds__(512) void k_fattn(
    const unsigned short* __restrict__ qb, const unsigned short* __restrict__ kb,
    const unsigned short* __restrict__ vtb, void* __restrict__ outp,
    const int* __restrict__ flag) {
  __shared__ unsigned short pl[2][8][16][74];
  __shared__ float accb[8][16][66];
  __shared__ float lb[8][16];
  int tid = threadIdx.x;
  int w = tid >> 6, lane = tid & 63;
  int col = lane & 15, quad = lane >> 4;
  int qt = w >> 2, kh = w & 3;
  int b = blockIdx.x >> 5;
  int n0 = (blockIdx.x & 31) * 32;
  long gbase = (long)b * NN;
  const unsigned short* vrow = vtb + (long)b*HID*NN;

  s8v aq = *(const s8v*)(qb + (gbase + n0 + qt*16 + col)*DKK + quad*8);

  f4v acc[4];
#pragma unroll
  for (int t = 0; t < 4; ++t) acc[t] = (f4v){0.f,0.f,0.f,0.f};
  float psum[4] = {0.f,0.f,0.f,0.f};
  const float rs = 0.17677669529663687f;
  const int cbeg = kh * 256;

#pragma unroll 2
  for (int it = 0; it < 4; ++it) {
    int c0 = cbeg + it*64;
    int pb = it & 1;
    f4v s4[4];
#pragma unroll
    for (int nt = 0; nt < 4; ++nt) {
      s8v bk = *(const s8v*)(kb + (gbase + c0 + nt*16 + col)*DKK + quad*8);
      s4[nt] = __builtin_amdgcn_mfma_f32_16x16x32_bf16(aq, bk,
                (f4v){0.f,0.f,0.f,0.f}, 0, 0, 0);
    }
#pragma unroll
    for (int r = 0; r < 4; ++r) {
      float p0 = expf(s4[0][r]*rs), p1 = expf(s4[1][r]*rs);
      float p2 = expf(s4[2][r]*rs), p3 = expf(s4[3][r]*rs);
      psum[r] += (p0 + p1) + (p2 + p3);
      int row = quad*4 + r;
      pl[pb][w][row][col]      = f2b(p0);
      pl[pb][w][row][16 + col] = f2b(p1);
      pl[pb][w][row][32 + col] = f2b(p2);
      pl[pb][w][row][48 + col] = f2b(p3);
    }
#pragma unroll
    for (int ks = 0; ks < 2; ++ks) {
      s8v ap = *(const s8v*)&pl[pb][w][col][ks*32 + quad*8];
#pragma unroll
      for (int nt = 0; nt < 4; ++nt) {
        s8v bv = *(const s8v*)(vrow + (long)(nt*16 + col)*NN + c0 + ks*32 + quad*8);
        acc[nt] = __builtin_amdgcn_mfma_f32_16x16x32_bf16(ap, bv, acc[nt], 0, 0, 0);
      }
    }
  }

#pragma unroll
  for (int r = 0; r < 4; ++r) {
    float v = psum[r];
#pragma unroll
    for (int off = 1; off < 16; off <<= 1) v += __shfl_xor(v, off);
    psum[r] = v;
  }
#pragma unroll
  for (int t = 0; t < 4; ++t)
#pragma unroll
    for (int r = 0; r < 4; ++r)
      accb[w][quad*4 + r][t*16 + col] = acc[t][r];
  if (col == 0) {
#pragma unroll
    for (int r = 0; r < 4; ++r) lb[w][quad*4 + r] = psum[r];
  }
  __syncthreads();

  int f = *flag;
#pragma unroll
  for (int rr = 0; rr < 4; ++rr) {
    int rl = w*4 + rr;                 // 0..31
    int qtt = rl >> 4, lrr = rl & 15;
    float a = accb[4*qtt][lrr][lane] + accb[4*qtt + 1][lrr][lane]
            + accb[4*qtt + 2][lrr][lane] + accb[4*qtt + 3][lrr][lane];
    float l = lb[4*qtt][lrr] + lb[4*qtt + 1][lrr]
            + lb[4*qtt + 2][lrr] + lb[4*qtt + 3][lrr];
    float val = a / l;
    long idx = (gbase + n0 + rl)*HID + lane;
    if (f) ((float*)outp)[idx] = val;
    else   ((bf16*)outp)[idx] = __float2bfloat16(val);
  }
}

// ================================================================ launch
extern "C" void kernel_launch(void* const* d_in, const int* in_sizes, int n_in,
                              void* d_out, int out_size, void* d_ws, size_t ws_size,
                              hipStream_t stream) {
  static const int EXP[30] = {
    49152, 49152, 384, 128, 49152, 768, 16384, 256,
    524288, 8192, 524288, 256, 256, 256, 256, 256,
    8192, 8192, 16384, 524288, 8192, 524288, 256, 256,
    256, 256, 256, 4096, 4096, 8192
  };
  // z[2] + enc + qb + kb + vt + wcw  (floats)
  const size_t NEED = (size_t)(2*ZS + 524288 + 524288 + 524288 + 1048576 + 1048576) * 4 + 64;
  bool ok = (n_in == 30) && (ws_size >= NEED) && (out_size == BB*NN*HID);
  if (ok) for (int i = 0; i < 30; ++i) ok = ok && (in_sizes[i] == EXP[i]);
  if (!ok) {
    k_zero<<<(BB*NN*HID + 255)/256, 256, 0, stream>>>((unsigned short*)d_out, BB*NN*HID);
    return;
  }

  float* z   = (float*)d_ws;             // 2 × [4,1024,4,64]
  float* enc = z   + 2*ZS;               // [4,1024,128]
  float* qb  = enc + 524288;             // bf16 q [32 groups][1024][32]
  float* kb  = qb  + 524288;             // bf16 k
  float* vb  = kb  + 524288;             // bf16 V^T [32 groups][64][1024]
  float* wcf = vb  + 1048576;            // bf16 FF weights [4 si][4][131072]
  int*  flag = (int*)(wcf + 1048576);
  unsigned short* wcw = (unsigned short*)wcf;

  k_detect<<<1, 256, 0, stream>>>(d_in[0], flag);

  const void *i_traffic=d_in[0], *i_user=d_in[1], *i_pw=d_in[2], *i_pb=d_in[3],
    *i_mw=d_in[4], *i_mb=d_in[5], *i_ow=d_in[6], *i_ob=d_in[7], *i_f1w=d_in[8],
    *i_f1b=d_in[9], *i_f2w=d_in[10], *i_f2b=d_in[11], *i_l1g=d_in[12],
    *i_l1b=d_in[13], *i_l2g=d_in[14], *i_l2b=d_in[15], *i_gwq=d_in[16],
    *i_gwk=d_in[17], *i_gwv=d_in[18], *i_gf1w=d_in[19], *i_gf1b=d_in[20],
    *i_gf2w=d_in[21], *i_gf2b=d_in[22], *i_gl1g=d_in[23], *i_gl1b=d_in[24],
    *i_gl2g=d_in[25], *i_gl2b=d_in[26], *i_cwq=d_in[27], *i_cwk=d_in[28],
    *i_cwv=d_in[29];

  // all 16 FF weight matrices, one dispatch
  k_wconv<<<1024, 256, 0, stream>>>(i_f1w, i_f2w, i_gf1w, i_gf2w, wcw, flag);

  // layer 0: patch -> tattn -> FF -> gqkv, then graph attention
  k_tff<<<512, 256, 0, stream>>>(z,
      i_traffic, i_user, i_pw, i_pb,
      i_mw, i_mb, i_ow, i_ob,
      i_l1g, i_l1b, wcw, 0, i_f1b, i_f2b, i_l2g, i_l2b,
      i_gf1b, i_gf2b, i_gl2g, i_gl2b,
      i_gwq, i_gwk, i_gwv,
      (unsigned short*)qb, (unsigned short*)kb, (unsigned short*)vb, flag);
  k_gattn<<<1024, 512, 0, stream>>>(z,
      (const unsigned short*)qb, (const unsigned short*)kb,
      (const unsigned short*)vb, i_gl1g, i_gl1b, 0, flag);
  // layer 1: gaFF(layer0) -> tattn -> FF -> gqkv
  k_tff<<<512, 256, 0, stream>>>(z,
      i_traffic, i_user, i_pw, i_pb,
      i_mw, i_mb, i_ow, i_ob,
      i_l1g, i_l1b, wcw, 1, i_f1b, i_f2b, i_l2g, i_l2b,
      i_gf1b, i_gf2b, i_gl2g, i_gl2b,
      i_gwq, i_gwk, i_gwv,
      (unsigned short*)qb, (unsigned short*)kb, (unsigned short*)vb, flag);
  // fused graph attention + gaFF(layer1) + pool -> enc
  k_gaf<<<512, 256, 0, stream>>>(z,
      (const unsigned short*)qb, (const unsigned short*)kb,
      (const unsigned short*)vb, i_gl1g, i_gl1b, wcw,
      i_gf1b, i_gf2b, i_gl2g, i_gl2b, enc, flag);

  k_fqkv<<<BB*NN, 128, 0, stream>>>(enc, i_cwq, i_cwk, i_cwv,
      (unsigned short*)qb, (unsigned short*)kb, (unsigned short*)vb, flag);
  k_fattn<<<BB*32, 512, 0, stream>>>((const unsigned short*)qb,
      (const unsigned short*)kb, (unsigned short*)vb, d_out, flag);
}

// Round 19
// 568.189 us; speedup vs baseline: 1.0337x; 1.0337x over previous
//
#include <hip/hip_runtime.h>
#include <hip/hip_bf16.h>
#include <math.h>

// Problem constants
#define BB 4
#define SEQL 12
#define NN 1024
#define SEGL 3
#define SEGN 4
#define HID 64
#define FFD 2048
#define DKK 32
#define NHH 8
#define HDD 8
#define ZS 1048576   // floats per z stream [4,1024,4,64]

using bf16 = __hip_bfloat16;
__device__ __forceinline__ float b2f(bf16 v) { return __bfloat162float(v); }

typedef __attribute__((ext_vector_type(8))) short s8v;   // 8 bf16 (4 VGPRs)
typedef __attribute__((ext_vector_type(4))) float f4v;   // MFMA C/D
typedef __attribute__((ext_vector_type(4))) unsigned short u4v;

__device__ __forceinline__ unsigned short f2b(float f) {
  bf16 h = __float2bfloat16(f);
  unsigned short u; __builtin_memcpy(&u, &h, 2); return u;
}
__device__ __forceinline__ float us2f(unsigned short u) {
  unsigned int e = ((unsigned int)u) << 16;
  float f; __builtin_memcpy(&f, &e, 4); return f;
}

// dtype-templated loads: F=1 fp32 storage, F=0 bf16 storage
template <int F>
__device__ __forceinline__ float ldw(const void* p, long i) {
  if (F) return ((const float*)p)[i];
  return b2f(((const bf16*)p)[i]);
}
template <int F>
__device__ __forceinline__ s8v ldfrag(const void* p, long elemOff) {
  if (F) {
    const float* fp = (const float*)p + elemOff;
    f4v u = *(const f4v*)fp, v = *(const f4v*)(fp + 4);
    s8v t;
    t[0]=f2b(u[0]); t[1]=f2b(u[1]); t[2]=f2b(u[2]); t[3]=f2b(u[3]);
    t[4]=f2b(v[0]); t[5]=f2b(v[1]); t[6]=f2b(v[2]); t[7]=f2b(v[3]);
    return t;
  }
  return *(const s8v*)((const unsigned short*)p + elemOff);
}
template <int F>
__device__ __forceinline__ f4v ldb4(const void* p, long i) {  // 4 consecutive vals
  if (F) return *(const f4v*)((const float*)p + i);
  u4v u = *(const u4v*)((const unsigned short*)p + i);
  f4v r; r[0]=us2f(u[0]); r[1]=us2f(u[1]); r[2]=us2f(u[2]); r[3]=us2f(u[3]);
  return r;
}

// ---------------------------------------------------------------- zero-fill d_out (guard path)
__global__ void k_zero(unsigned short* __restrict__ o, int n) {
  int i = blockIdx.x * 256 + threadIdx.x;
  if (i < n) o[i] = 0;
}

// ---------------------------------------------------------------- detect dtype
__global__ void k_detect(const void* __restrict__ x0, int* __restrict__ flag) {
  int t = threadIdx.x;
  int bad = 0;
  const bf16* p = (const bf16*)x0;
  for (int i = t; i < 512; i += 256) {
    float a = fabsf(b2f(p[i]));
    if (!(a < 1e4f) || (a != 0.f && a < 1e-4f)) bad = 1;
  }
  __shared__ int tot;
  if (t == 0) tot = 0;
  __syncthreads();
  unsigned long long m = __ballot(bad);
  if ((t & 63) == 0) atomicAdd(&tot, __popcll(m));
  __syncthreads();
  if (t == 0) *flag = (tot > 64) ? 1 : 0;   // 1 = fp32 storage, 0 = bf16
}

// ---------------------------------------------------------------- weight convert, ALL 16 FF mats
// layout: [si 0..3][which 0..3][131072], which: 0=ff1 1=ff2 2=ga_ff1 3=ga_ff2
template <int F>
__device__ __forceinline__ void wconv_body(const void* __restrict__ w1,
    const void* __restrict__ w2, const void* __restrict__ w3,
    const void* __restrict__ w4, unsigned short* __restrict__ out) {
  int i = blockIdx.x * 256 + threadIdx.x;
  long e8 = (long)i * 8;
  int slot = (int)(e8 >> 17);       // 0..15
  int si = slot >> 2, which = slot & 3;
  long r = e8 & 131071;
  const void* src = (which == 0) ? w1 : (which == 1) ? w2 : (which == 2) ? w3 : w4;
  *(s8v*)(out + e8) = ldfrag<F>(src, (long)si*FFD*HID + r);
}
__global__ __launch_bounds__(256) void k_wconv(const void* w1, const void* w2,
    const void* w3, const void* w4, unsigned short* out,
    const int* __restrict__ flag) {
  if (*flag) wconv_body<1>(w1, w2, w3, w4, out);
  else       wconv_body<0>(w1, w2, w3, w4, out);
}

// ---------------------------------------------------------------- FF staging helpers (v11)
#define TT 64
#define FRW 64
#define HCS 74

__device__ __forceinline__ void ff_ld(const unsigned short* __restrict__ wc1,
    const unsigned short* __restrict__ wc2, int hb, int srow, int le,
    s8v* r1, s8v* r2) {
  r1[0] = *(const s8v*)(wc1 + (long)(hb + srow)*HID + le*8);
  r1[1] = *(const s8v*)(wc1 + (long)(hb + srow + 8)*HID + le*8);
  r2[0] = *(const s8v*)(wc2 + (long)srow*FFD + hb + le*8);
  r2[1] = *(const s8v*)(wc2 + (long)(srow + 8)*FFD + hb + le*8);
}
__device__ __forceinline__ void ff_wr(char* ldsbuf, int pb, int srow, int swb,
    const s8v* r1, const s8v* r2) {
  char* w1b = ldsbuf + pb*8192;
  char* w2b = ldsbuf + 16384 + pb*8192;
  *(s8v*)(w1b + srow*128 + swb) = r1[0];
  *(s8v*)(w1b + (srow + 8)*128 + swb) = r1[1];
  *(s8v*)(w2b + srow*128 + swb) = r2[0];
  *(s8v*)(w2b + (srow + 8)*128 + swb) = r2[1];
}
// one 64-h compute step: FF1 tile -> ReLU -> hcw; FF2 partial into acc
template <int F>
__device__ __forceinline__ void ff_compute(const char* ldsbuf, int pb, int hb,
    int col, int quad, int sw, const s8v* bx, unsigned short* hcw,
    const void* __restrict__ B1, long ob1, f4v* acc) {
  const char* w1b = ldsbuf + pb*8192;
  const char* w2b = ldsbuf + 16384 + pb*8192;
#pragma unroll
  for (int t = 0; t < 4; ++t) {
    int row = t*16 + col;
    s8v a10 = *(const s8v*)(w1b + row*128 + ((quad*16) ^ sw));
    s8v a11 = *(const s8v*)(w1b + row*128 + ((64 + quad*16) ^ sw));
    f4v bv = ldb4<F>(B1, ob1 + hb + t*16 + quad*4);
    f4v sv = __builtin_amdgcn_mfma_f32_16x16x32_bf16(a10, bx[0],
               (f4v){0.f,0.f,0.f,0.f}, 0, 0, 0);
    sv = __builtin_amdgcn_mfma_f32_16x16x32_bf16(a11, bx[1], sv, 0, 0, 0);
    unsigned short pk[4];
#pragma unroll
    for (int r = 0; r < 4; ++r) pk[r] = f2b(fmaxf(sv[r] + bv[r], 0.f));
    *(unsigned long long*)&hcw[col*HCS + t*16 + quad*4] =
      (unsigned long long)pk[0] | ((unsigned long long)pk[1] << 16) |
      ((unsigned long long)pk[2] << 32) | ((unsigned long long)pk[3] << 48);
  }
#pragma unroll
  for (int ks2 = 0; ks2 < 2; ++ks2) {
    s8v bh = *(const s8v*)&hcw[col*HCS + ks2*32 + quad*8];
#pragma unroll
    for (int m = 0; m < 4; ++m) {
      int r2 = m*16 + col;
      s8v a2 = *(const s8v*)(w2b + r2*128 + ((ks2*64 + quad*16) ^ sw));
      acc[m] = __builtin_amdgcn_mfma_f32_16x16x32_bf16(a2, bh, acc[m], 0, 0, 0);
    }
  }
}
// full 32-step depth-2-pipelined FF pass (acc accumulates FF2 partials)
template <int F>
__device__ __forceinline__ void ff_run(char* ldsbuf,
    const unsigned short* __restrict__ wc1, const unsigned short* __restrict__ wc2,
    const void* __restrict__ B1, long ob1, const s8v* bx, unsigned short* hcw,
    int col, int quad, int sw, int srow, int le, int swb, f4v* acc) {
  s8v c1[2], c2[2], rA1[2], rA2[2], rB1[2], rB2[2];
  ff_ld(wc1, wc2, 0, srow, le, c1, c2);
  ff_wr(ldsbuf, 0, srow, swb, c1, c2);
  ff_ld(wc1, wc2, 64, srow, le, rA1, rA2);
  ff_ld(wc1, wc2, 128, srow, le, rB1, rB2);
  __syncthreads();
  for (int c = 0; c < 32; c += 2) {
    ff_compute<F>(ldsbuf, 0, c*64, col, quad, sw, bx, hcw, B1, ob1, acc);
    ff_wr(ldsbuf, 1, srow, swb, rA1, rA2);
    if (c + 3 < 32) ff_ld(wc1, wc2, (c+3)*64, srow, le, rA1, rA2);
    __syncthreads();
    ff_compute<F>(ldsbuf, 1, (c+1)*64, col, quad, sw, bx, hcw, B1, ob1, acc);
    if (c + 2 < 32) ff_wr(ldsbuf, 0, srow, swb, rB1, rB2);
    if (c + 4 < 32) ff_ld(wc1, wc2, (c+4)*64, srow, le, rB1, rB2);
    __syncthreads();
  }
}

// ---------------------------------------------------------------- FUSED {patch | gaFF(prev)} + temporal attn + FF + graph qkv (k_tff)
template <int F>
__device__ __forceinline__ void tff_body(float* __restrict__ zb,
    const void* __restrict__ xt, const void* __restrict__ xu,
    const void* __restrict__ pw, const void* __restrict__ pbp,
    const void* __restrict__ W, const void* __restrict__ bq,
    const void* __restrict__ WO, const void* __restrict__ bo,
    const void* __restrict__ g1, const void* __restrict__ b1,
    const unsigned short* __restrict__ wcw, int li,
    const void* __restrict__ B1, const void* __restrict__ B2,
    const void* __restrict__ G, const void* __restrict__ Bt,
    const void* __restrict__ pgf1b, const void* __restrict__ pgf2b,
    const void* __restrict__ pgl2g, const void* __restrict__ pgl2b,
    const void* __restrict__ gwq, const void* __restrict__ gwk,
    const void* __restrict__ gwv,
    unsigned short* __restrict__ qo, unsigned short* __restrict__ ko,
    unsigned short* __restrict__ vto,
    char* lds) {
  int s = blockIdx.x >> 8, blk = blockIdx.x & 255;
  long si = s*2 + li;
  float* z = zb + (long)s*ZS;
  long oW = si*3*HID*HID, obq = si*3*HID, oWO = si*HID*HID, obo = si*HID;
  long og1 = si*HID, ob1 = si*HID;
  const unsigned short* wc1 = wcw + (si*4 + 0)*131072;
  const unsigned short* wc2 = wcw + (si*4 + 1)*131072;
  long fob1 = si*FFD, fob2 = si*HID, fog = si*HID, fobt = si*HID;
  unsigned short (*qkvs)[200] = (unsigned short(*)[200])lds;        // 25600 B
  unsigned short (*ao)[72]    = (unsigned short(*)[72])(lds + 25600); // 9216 B
  float (*yb)[68]             = (float(*)[68])(lds + 34816);          // 17408 B
  int tid = threadIdx.x;
  int w = tid >> 6, lane = tid & 63;
  int col = lane & 15, quad = lane >> 4;
  long r0 = (long)blk * TT;
  float* stash = (float*)(lds + 59648);             // [64][68] block-wide
  float* stashW = stash + w*16*68;                  // wave's rows
  unsigned short* hcw = (unsigned short*)(lds + 32768 + w*2368);  // [16][74]
  float* red = (float*)(lds + 42240 + w*4352);                    // [16][68]
  int lr = lane >> 3, le = lane & 7;
  int srow = w*16 + lr;
  int swb = ((le ^ lr) << 4);
  const int sw = (col & 7) << 4;

  if (li == 0) {
    // ================= phase 0: patch embed -> stash =================
    const void* x = s ? xu : xt;
    long opw = (long)s*HID*SEGL, opb = (long)s*HID;
    float dv = expf((float)(2*(lane >> 1)) * (-logf(10000.f) / (float)HID));
    float pe[4];
#pragma unroll
    for (int g = 0; g < 4; ++g) {
      float ang = (float)g * dv;
      pe[g] = (lane & 1) ? cosf(ang) : sinf(ang);
    }
    float pbv = ldw<F>(pbp, opb + lane);
    float pwv[3];
#pragma unroll
    for (int l = 0; l < 3; ++l) pwv[l] = ldw<F>(pw, opw + lane*3 + l);
#pragma unroll
    for (int rr = 0; rr < 16; ++rr) {
      long tok = r0 + w*16 + rr;
      int b_ = (int)(tok >> 12);
      int n_ = (int)((tok >> 2) & 1023);
      int g_ = (int)(tok & 3);
      float a = pbv;
#pragma unroll
      for (int l = 0; l < 3; ++l)
        a += ldw<F>(x, (long)(b_*SEQL + g_*SEGL + l)*NN + n_) * pwv[l];
      stashW[rr*68 + lane] = a + pe[g_];
    }
    __syncthreads();
  } else {
    // ================= phase -1: gaFF of layer 0 -> stash =================
    long sip = s*2;                    // prev layer (li==0) slot
    const unsigned short* pw1 = wcw + (sip*4 + 2)*131072;
    const unsigned short* pw2 = wcw + (sip*4 + 3)*131072;
    long pob1 = sip*FFD, pob2 = sip*HID, pog = sip*HID, pobt = sip*HID;
    s8v bxp[2];
    {
      const float* xr = z + (r0 + w*16 + col) * HID;
#pragma unroll
      for (int ks = 0; ks < 2; ++ks) {
        const float* p = xr + ks*32 + quad*8;
        f4v u = *(const f4v*)p, v = *(const f4v*)(p + 4);
        s8v t;
        t[0]=f2b(u[0]); t[1]=f2b(u[1]); t[2]=f2b(u[2]); t[3]=f2b(u[3]);
        t[4]=f2b(v[0]); t[5]=f2b(v[1]); t[6]=f2b(v[2]); t[7]=f2b(v[3]);
        bxp[ks] = t;
      }
    }
    f4v accp[4];
#pragma unroll
    for (int m = 0; m < 4; ++m) accp[m] = (f4v){0.f,0.f,0.f,0.f};
    ff_run<F>(lds, pw1, pw2, pgf1b, pob1, bxp, hcw, col, quad, sw, srow, le, swb, accp);
#pragma unroll
    for (int m = 0; m < 4; ++m)
      *(f4v*)&red[col*68 + m*16 + quad*4] = accp[m];
    float pgg = ldw<F>(pgl2g, pog + lane), pbb = ldw<F>(pgl2b, pobt + lane);
    float pb2 = ldw<F>(pgf2b, pob2 + lane);
#pragma unroll
    for (int rr = 0; rr < 16; ++rr) {
      long grow = r0 + w*16 + rr;
      float val = red[rr*68 + lane] + pb2 + z[grow*HID + lane];
      float sm = val;
#pragma unroll
      for (int off = 32; off; off >>= 1) sm += __shfl_xor(sm, off);
      float m = sm * (1.f/HID);
      float d = val - m;
      float sq = d*d;
#pragma unroll
      for (int off = 32; off; off >>= 1) sq += __shfl_xor(sq, off);
      float rv = rsqrtf(sq*(1.f/HID) + 1e-5f);
      stashW[rr*68 + lane] = d*rv*pgg + pbb;
    }
    __syncthreads();
  }

  // ================= phase 1: temporal attention (input from stash) =================
  s8v bx[4][2];
#pragma unroll
  for (int mt = 0; mt < 4; ++mt) {
    const float* xr = &stash[(mt*16 + col)*68];
#pragma unroll
    for (int ks = 0; ks < 2; ++ks) {
      const float* p = xr + ks*32 + quad*8;
      f4v u = *(const f4v*)p, v = *(const f4v*)(p + 4);
      s8v t;
      t[0]=f2b(u[0]); t[1]=f2b(u[1]); t[2]=f2b(u[2]); t[3]=f2b(u[3]);
      t[4]=f2b(v[0]); t[5]=f2b(v[1]); t[6]=f2b(v[2]); t[7]=f2b(v[3]);
      bx[mt][ks] = t;
    }
  }
#pragma unroll
  for (int nt = 0; nt < 3; ++nt) {
    int cbase = (w*3 + nt) * 16;
    s8v aw[2];
#pragma unroll
    for (int ks = 0; ks < 2; ++ks)
      aw[ks] = ldfrag<F>(W, oW + (long)(cbase + col)*HID + ks*32 + quad*8);
    f4v bv = ldb4<F>(bq, obq + cbase + quad*4);
#pragma unroll
    for (int mt = 0; mt < 4; ++mt) {
      f4v sv = (f4v){0.f,0.f,0.f,0.f};
#pragma unroll
      for (int ks = 0; ks < 2; ++ks)
        sv = __builtin_amdgcn_mfma_f32_16x16x32_bf16(aw[ks], bx[mt][ks], sv, 0, 0, 0);
      unsigned short pk[4];
#pragma unroll
      for (int r = 0; r < 4; ++r) pk[r] = f2b(sv[r] + bv[r]);
      *(unsigned long long*)&qkvs[mt*16 + col][cbase + quad*4] =
        (unsigned long long)pk[0] | ((unsigned long long)pk[1] << 16) |
        ((unsigned long long)pk[2] << 32) | ((unsigned long long)pk[3] << 48);
    }
  }
  __syncthreads();
  if (tid < 128) {
    int gi = tid >> 3, hd = tid & 7;
    int tl = gi * 4;
    float qv[4][8], kv[4][8], vv[4][8];
#pragma unroll
    for (int t4 = 0; t4 < 4; ++t4) {
      s8v qq = *(const s8v*)&qkvs[tl + t4][hd*8];
      s8v kk = *(const s8v*)&qkvs[tl + t4][64 + hd*8];
      s8v vq = *(const s8v*)&qkvs[tl + t4][128 + hd*8];
#pragma unroll
      for (int e = 0; e < 8; ++e) {
        qv[t4][e] = us2f((unsigned short)qq[e]);
        kv[t4][e] = us2f((unsigned short)kk[e]);
        vv[t4][e] = us2f((unsigned short)vq[e]);
      }
    }
    const float sc8 = 0.3535533905932738f;   // 1/sqrt(8)
#pragma unroll
    for (int qt = 0; qt < 4; ++qt) {
      float sc[4]; float mx = -1e30f;
#pragma unroll
      for (int kt = 0; kt < 4; ++kt) {
        float d = 0;
#pragma unroll
        for (int e = 0; e < 8; ++e) d += qv[qt][e]*kv[kt][e];
        sc[kt] = d*sc8; mx = fmaxf(mx, sc[kt]);
      }
      float se = 0;
#pragma unroll
      for (int kt = 0; kt < 4; ++kt) { sc[kt] = expf(sc[kt]-mx); se += sc[kt]; }
      float inv = 1.f/se;
      s8v outp;
#pragma unroll
      for (int e = 0; e < 8; ++e) {
        float o = 0;
#pragma unroll
        for (int kt = 0; kt < 4; ++kt) o += sc[kt]*vv[kt][e];
        outp[e] = (short)f2b(o*inv);
      }
      *(s8v*)&ao[tl + qt][hd*8] = outp;
    }
  }
  __syncthreads();
  s8v awo[2];
#pragma unroll
  for (int ks = 0; ks < 2; ++ks)
    awo[ks] = ldfrag<F>(WO, oWO + (long)(w*16 + col)*HID + ks*32 + quad*8);
  f4v bov = ldb4<F>(bo, obo + w*16 + quad*4);
#pragma unroll
  for (int mt = 0; mt < 4; ++mt) {
    f4v ov = (f4v){0.f,0.f,0.f,0.f};
#pragma unroll
    for (int ks = 0; ks < 2; ++ks) {
      s8v bao = *(const s8v*)&ao[mt*16 + col][ks*32 + quad*8];
      ov = __builtin_amdgcn_mfma_f32_16x16x32_bf16(awo[ks], bao, ov, 0, 0, 0);
    }
    f4v yv;
#pragma unroll
    for (int r = 0; r < 4; ++r) yv[r] = ov[r] + bov[r];
    *(f4v*)&yb[mt*16 + col][w*16 + quad*4] = yv;
  }
  __syncthreads();
  {
    float gg = ldw<F>(g1, og1 + lane), bb2 = ldw<F>(b1, ob1 + lane);
#pragma unroll
    for (int rr = 0; rr < 16; ++rr) {
      int row = w*16 + rr;
      float val = yb[row][lane] + stashW[rr*68 + lane];
      float sm = val;
#pragma unroll
      for (int off = 32; off; off >>= 1) sm += __shfl_xor(sm, off);
      float m = sm*(1.f/HID);
      float d = val - m, sq = d*d;
#pragma unroll
      for (int off = 32; off; off >>= 1) sq += __shfl_xor(sq, off);
      float rv = rsqrtf(sq*(1.f/HID) + 1e-5f);
      stashW[rr*68 + lane] = d*rv*gg + bb2;     // LN1 -> stash (in-place safe)
    }
  }
  __syncthreads();   // attn LDS dead; FF regions may now be written

  // ================= phase 2: FF (depth-2 pipeline) =================
  s8v bx2[2];
#pragma unroll
  for (int ks = 0; ks < 2; ++ks) {
    const float* p = &stashW[col*68 + ks*32 + quad*8];
    f4v u = *(const f4v*)p, v = *(const f4v*)(p + 4);
    s8v t;
    t[0]=f2b(u[0]); t[1]=f2b(u[1]); t[2]=f2b(u[2]); t[3]=f2b(u[3]);
    t[4]=f2b(v[0]); t[5]=f2b(v[1]); t[6]=f2b(v[2]); t[7]=f2b(v[3]);
    bx2[ks] = t;
  }

  f4v acc[4];
#pragma unroll
  for (int m = 0; m < 4; ++m) acc[m] = (f4v){0.f,0.f,0.f,0.f};
  ff_run<F>(lds, wc1, wc2, B1, fob1, bx2, hcw, col, quad, sw, srow, le, swb, acc);

#pragma unroll
  for (int m = 0; m < 4; ++m)
    *(f4v*)&red[col*68 + m*16 + quad*4] = acc[m];
  float* finb = (float*)lds;     // [64][68], overlays wdbuf (dead after loop)
  {
    float fgg = ldw<F>(G, fog + lane), fbbt = ldw<F>(Bt, fobt + lane);
    float b2v = ldw<F>(B2, fob2 + lane);
#pragma unroll
    for (int rr = 0; rr < 16; ++rr) {
      long grow = r0 + w*16 + rr;
      float val = red[rr*68 + lane] + b2v + stashW[rr*68 + lane];
      float sm = val;
#pragma unroll
      for (int off = 32; off; off >>= 1) sm += __shfl_xor(sm, off);
      float m = sm * (1.f/HID);
      float d = val - m;
      float sq = d*d;
#pragma unroll
      for (int off = 32; off; off >>= 1) sq += __shfl_xor(sq, off);
      float rv = rsqrtf(sq*(1.f/HID) + 1e-5f);
      float fin = d*rv*fgg + fbbt;
      z[grow*HID + lane] = fin;
      finb[(w*16 + rr)*68 + lane] = fin;
    }
  }
  __syncthreads();   // finb visible block-wide

  // ================= phase 3: fused graph qkv =================
  long oq = si*DKK*HID, okk = si*DKK*HID, ovv = si*HID*HID;
  s8v bx3[4][2];
#pragma unroll
  for (int rt = 0; rt < 4; ++rt)
#pragma unroll
    for (int ks = 0; ks < 2; ++ks) {
      const float* p = &finb[(rt*16 + col)*68 + ks*32 + quad*8];
      f4v u = *(const f4v*)p, v = *(const f4v*)(p + 4);
      s8v t;
      t[0]=f2b(u[0]); t[1]=f2b(u[1]); t[2]=f2b(u[2]); t[3]=f2b(u[3]);
      t[4]=f2b(v[0]); t[5]=f2b(v[1]); t[6]=f2b(v[2]); t[7]=f2b(v[3]);
      bx3[rt][ks] = t;
    }
#pragma unroll
  for (int tt = 0; tt < 2; ++tt) {
    int ct = w*2 + tt;                        // wave-uniform
    const void* wp; long wo; int co; int kind; // 0=q,1=k,2=v
    if (ct < 2)      { wp = gwq; wo = oq;  co = ct*16;      kind = 0; }
    else if (ct < 4) { wp = gwk; wo = okk; co = (ct-2)*16;  kind = 1; }
    else             { wp = gwv; wo = ovv; co = (ct-4)*16;  kind = 2; }
    s8v aw[2];
#pragma unroll
    for (int ks = 0; ks < 2; ++ks)
      aw[ks] = ldfrag<F>(wp, wo + (long)(co + col)*HID + ks*32 + quad*8);
#pragma unroll
    for (int rt = 0; rt < 4; ++rt) {
      f4v sv = (f4v){0.f,0.f,0.f,0.f};
#pragma unroll
      for (int ks = 0; ks < 2; ++ks)
        sv = __builtin_amdgcn_mfma_f32_16x16x32_bf16(aw[ks], bx3[rt][ks], sv, 0, 0, 0);
      long tok2 = r0 + rt*16 + col;
      int b_ = (int)(tok2 >> 12);
      int n_ = (int)((tok2 >> 2) & 1023);
      int g_ = (int)(tok2 & 3);
      int sgl = s*16 + b_*4 + g_;
      if (kind == 2) {
        long vbase = (long)sgl*HID*NN;
#pragma unroll
        for (int r = 0; r < 4; ++r)
          vto[vbase + (long)(co + quad*4 + r)*NN + n_] = f2b(sv[r]);
      } else {
        long row = (long)sgl*NN + n_;
        unsigned short pk[4];
#pragma unroll
        for (int r = 0; r < 4; ++r) pk[r] = f2b(sv[r]);
        unsigned short* dst = kind ? ko : qo;
        *(unsigned long long*)&dst[row*DKK + co + quad*4] =
          (unsigned long long)pk[0] | ((unsigned long long)pk[1] << 16) |
          ((unsigned long long)pk[2] << 32) | ((unsigned long long)pk[3] << 48);
      }
    }
  }
}
__global__ __launch_bounds__(256) void k_tff(float* __restrict__ z,
    const void* xt, const void* xu, const void* pw, const void* pbp,
    const void* W, const void* bqkv, const void* WO, const void* bo,
    const void* g1, const void* b1,
    const unsigned short* __restrict__ wcw, int li,
    const void* B1, const void* B2, const void* G, const void* Bt,
    const void* pgf1b, const void* pgf2b, const void* pgl2g, const void* pgl2b,
    const void* gwq, const void* gwk, const void* gwv,
    unsigned short* qo, unsigned short* ko, unsigned short* vto,
    const int* __restrict__ flag) {
  __shared__ __attribute__((aligned(16))) char lds[77056];
  if (*flag) tff_body<1>(z, xt, xu, pw, pbp, W, bqkv, WO, bo, g1, b1, wcw, li,
                         B1, B2, G, Bt, pgf1b, pgf2b, pgl2g, pgl2b,
                         gwq, gwk, gwv, qo, ko, vto, lds);
  else       tff_body<0>(z, xt, xu, pw, pbp, W, bqkv, WO, bo, g1, b1, wcw, li,
                         B1, B2, G, Bt, pgf1b, pgf2b, pgl2g, pgl2b,
                         gwq, gwk, gwv, qo, ko, vto, lds);
}

// ---------------------------------------------------------------- FF via MFMA bf16 (v11 + fused pool)
template <int F>
__device__ __forceinline__ void ffmfma_body(float* __restrict__ xb,
    const unsigned short* __restrict__ wcw, int li, int wsel,
    const void* __restrict__ B1, const void* __restrict__ B2,
    const void* __restrict__ G, const void* __restrict__ Bt,
    float* __restrict__ enc, int dop,
    char* ldsbuf) {
  int s = blockIdx.x >> 8, blk = blockIdx.x & 255;
  long si = s*2 + li;
  float* x = xb + (long)s*ZS;
  const unsigned short* wc1 = wcw + (si*4 + wsel)*131072;
  const unsigned short* wc2 = wcw + (si*4 + wsel + 1)*131072;
  long ob1 = si*FFD, ob2 = si*HID, og = si*HID, obt = si*HID;
  int tid = threadIdx.x;
  int w = tid >> 6, lane = tid & 63;
  int col = lane & 15, quad = lane >> 4;
  long r0 = (long)blk * FRW;
  unsigned short* hcw = (unsigned short*)(ldsbuf + 32768 + w*2368);  // [16 tok][74]
  float* red = (float*)(ldsbuf + w*4352);   // overlays wdbuf; used after final barrier

  long tokc = r0 + w*16 + col;
  s8v bx[2];
  {
    const float* xr = x + tokc * HID;
#pragma unroll
    for (int ks = 0; ks < 2; ++ks) {
      const float* p = xr + ks*32 + quad*8;
      f4v u = *(const f4v*)p, v = *(const f4v*)(p + 4);
      s8v t;
      t[0]=f2b(u[0]); t[1]=f2b(u[1]); t[2]=f2b(u[2]); t[3]=f2b(u[3]);
      t[4]=f2b(v[0]); t[5]=f2b(v[1]); t[6]=f2b(v[2]); t[7]=f2b(v[3]);
      bx[ks] = t;
    }
  }

  int lr = lane >> 3;
  int le = lane & 7;
  int srow = w*16 + lr;
  int swb = ((le ^ lr) << 4);
  const int sw = (col & 7) << 4;

  f4v acc[4];
#pragma unroll
  for (int m = 0; m < 4; ++m) acc[m] = (f4v){0.f,0.f,0.f,0.f};
  ff_run<F>(ldsbuf, wc1, wc2, B1, ob1, bx, hcw, col, quad, sw, srow, le, swb, acc);

#pragma unroll
  for (int m = 0; m < 4; ++m)
    *(f4v*)&red[col*68 + m*16 + quad*4] = acc[m];
  float gg = ldw<F>(G, og + lane), bbt = ldw<F>(Bt, obt + lane);
  float b2v = ldw<F>(B2, ob2 + lane);
  float pacc[4] = {0.f,0.f,0.f,0.f};
#pragma unroll
  for (int rr = 0; rr < 16; ++rr) {
    long grow = r0 + w*16 + rr;
    float val = red[rr*68 + lane] + b2v + x[grow*HID + lane];
    float sm = val;
#pragma unroll
    for (int off = 32; off; off >>= 1) sm += __shfl_xor(sm, off);
    float m = sm * (1.f/HID);
    float d = val - m;
    float sq = d*d;
#pragma unroll
    for (int off = 32; off; off >>= 1) sq += __shfl_xor(sq, off);
    float rv = rsqrtf(sq*(1.f/HID) + 1e-5f);
    float fin = d*rv*gg + bbt;
    x[grow*HID + lane] = fin;
    pacc[rr >> 2] += fin;
  }
  if (dop) {           // fused segment-pool: this tile = 16 whole nodes
#pragma unroll
    for (int j = 0; j < 4; ++j) {
      long tok = r0 + w*16 + j*4;
      enc[(tok >> 2)*(2*HID) + s*HID + lane] = pacc[j]*0.25f;
    }
  }
}
__global__ __launch_bounds__(256) void k_ffmfma(float* __restrict__ x,
    const unsigned short* __restrict__ wcw, int li, int wsel,
    const void* B1, const void* B2, const void* G, const void* Bt,
    float* enc, int dop, const int* __restrict__ flag) {
  __shared__ __attribute__((aligned(16))) char ldsbuf[42240];
  if (*flag) ffmfma_body<1>(x, wcw, li, wsel, B1, B2, G, Bt, enc, dop, ldsbuf);
  else       ffmfma_body<0>(x, wcw, li, wsel, B1, B2, G, Bt, enc, dop, ldsbuf);
}

// ---------------------------------------------------------------- graph attention (dual-s, 4-way key split)
// 1024 blocks: 32 queries/block, 4-way key split (kh=w&3, 256 keys each),
// 4-wave merge in LDS (no max state -> partial accs and sums just add).
__global__ __launch_bounds__(512) void k_gattn(float* __restrict__ zb,
    const unsigned short* __restrict__ qb, const unsigned short* __restrict__ kb,
    const unsigned short* __restrict__ vtb,
    const void* __restrict__ g1, const void* __restrict__ b1, int li,
    const int* __restrict__ flag) {
  int f = *flag;
  __shared__ unsigned short pl[2][8][16][74];  // ping-pong, wave-private, 74-pad
  __shared__ float accb[8][16][66];
  __shared__ float lb[8][16];
  int tid = threadIdx.x;
  int w = tid >> 6, lane = tid & 63;
  int col = lane & 15, quad = lane >> 4;
  int qt = w >> 2, kh = w & 3;
  int sg = blockIdx.x >> 5;              // 0..31
  int s = sg >> 4, bg = sg & 15;
  int n0 = (blockIdx.x & 31) * 32;
  long si = s*2 + li;
  float* z = zb + (long)s*ZS;
  long og1 = si*HID, ob1 = si*HID;
  long gbase = (long)sg * NN;
  const unsigned short* vrow = vtb + (long)sg*HID*NN;

  s8v aq = *(const s8v*)(qb + (gbase + n0 + qt*16 + col)*DKK + quad*8);

  f4v acc[4];
#pragma unroll
  for (int t = 0; t < 4; ++t) acc[t] = (f4v){0.f,0.f,0.f,0.f};
  float psum[4] = {0.f,0.f,0.f,0.f};
  const float rs = 0.17677669529663687f;   // 1/sqrt(32)
  const int cbeg = kh * 256;

#pragma unroll 2
  for (int it = 0; it < 4; ++it) {
    int c0 = cbeg + it*64;
    int pb = it & 1;
    f4v s4[4];
#pragma unroll
    for (int nt = 0; nt < 4; ++nt) {
      s8v bk = *(const s8v*)(kb + (gbase + c0 + nt*16 + col)*DKK + quad*8);
      s4[nt] = __builtin_amdgcn_mfma_f32_16x16x32_bf16(aq, bk,
                (f4v){0.f,0.f,0.f,0.f}, 0, 0, 0);
    }
#pragma unroll
    for (int r = 0; r < 4; ++r) {
      float p0 = expf(s4[0][r]*rs), p1 = expf(s4[1][r]*rs);
      float p2 = expf(s4[2][r]*rs), p3 = expf(s4[3][r]*rs);
      psum[r] += (p0 + p1) + (p2 + p3);
      int row = quad*4 + r;
      pl[pb][w][row][col]      = f2b(p0);
      pl[pb][w][row][16 + col] = f2b(p1);
      pl[pb][w][row][32 + col] = f2b(p2);
      pl[pb][w][row][48 + col] = f2b(p3);
    }
#pragma unroll
    for (int ks = 0; ks < 2; ++ks) {
      s8v ap = *(const s8v*)&pl[pb][w][col][ks*32 + quad*8];
#pragma unroll
      for (int nt = 0; nt < 4; ++nt) {
        s8v bv = *(const s8v*)(vrow + (long)(nt*16 + col)*NN + c0 + ks*32 + quad*8);
        acc[nt] = __builtin_amdgcn_mfma_f32_16x16x32_bf16(ap, bv, acc[nt], 0, 0, 0);
      }
    }
  }

#pragma unroll
  for (int r = 0; r < 4; ++r) {
    float v = psum[r];
#pragma unroll
    for (int off = 1; off < 16; off <<= 1) v += __shfl_xor(v, off);
    psum[r] = v;
  }
#pragma unroll
  for (int t = 0; t < 4; ++t)
#pragma unroll
    for (int r = 0; r < 4; ++r)
      accb[w][quad*4 + r][t*16 + col] = acc[t][r];
  if (col == 0) {
#pragma unroll
    for (int r = 0; r < 4; ++r) lb[w][quad*4 + r] = psum[r];
  }
  __syncthreads();

  int b = bg >> 2, g = bg & 3;
  float gg = f ? ((const float*)g1)[og1 + lane] : b2f(((const bf16*)g1)[og1 + lane]);
  float bb = f ? ((const float*)b1)[ob1 + lane] : b2f(((const bf16*)b1)[ob1 + lane]);
#pragma unroll
  for (int rr = 0; rr < 4; ++rr) {
    int rl = w*4 + rr;                 // 0..31
    int qtt = rl >> 4, lrr = rl & 15;
    float a = accb[4*qtt][lrr][lane] + accb[4*qtt + 1][lrr][lane]
            + accb[4*qtt + 2][lrr][lane] + accb[4*qtt + 3][lrr][lane];
    float l = lb[4*qtt][lrr] + lb[4*qtt + 1][lrr]
            + lb[4*qtt + 2][lrr] + lb[4*qtt + 3][lrr];
    float val = a / l;
    float s2 = val;
#pragma unroll
    for (int off = 32; off; off >>= 1) s2 += __shfl_xor(s2, off);
    float m = s2*(1.f/HID);
    float d = val - m, sq = d*d;
#pragma unroll
    for (int off = 32; off; off >>= 1) sq += __shfl_xor(sq, off);
    float r = rsqrtf(sq*(1.f/HID) + 1e-5f);
    float* zp = z + ((long)(b*NN + n0 + rl)*SEGN + g)*HID;
    zp[lane] = d*r*gg + bb + zp[lane];   // LN(att) + x
  }
}

// ---------------------------------------------------------------- final qkv proj (in_dim=128)
// v emitted as bf16 V^T: vt[b][dim 0..63][key 0..1023]
template <int F>
__device__ __forceinline__ void fqkv_body(const float* __restrict__ enc,
    const void* __restrict__ wq, const void* __restrict__ wk,
    const void* __restrict__ wv,
    unsigned short* __restrict__ q, unsigned short* __restrict__ k,
    unsigned short* __restrict__ vt, float* xs) {
  long r = blockIdx.x;
  int t = threadIdx.x;
  xs[t] = enc[r*128 + t];
  __syncthreads();
  if (t < 32) {
    long wr = (long)t*128; float a = 0;
    for (int e = 0; e < 128; ++e) a += xs[e]*ldw<F>(wq, wr + e);
    q[r*DKK + t] = f2b(a);
  } else if (t < 64) {
    long wr = (long)(t-32)*128; float a = 0;
    for (int e = 0; e < 128; ++e) a += xs[e]*ldw<F>(wk, wr + e);
    k[r*DKK + (t-32)] = f2b(a);
  } else {
    long wr = (long)(t-64)*128; float a = 0;
    for (int e = 0; e < 128; ++e) a += xs[e]*ldw<F>(wv, wr + e);
    vt[((r >> 10)*HID + (t-64))*NN + (r & 1023)] = f2b(a);
  }
}
__global__ __launch_bounds__(128) void k_fqkv(const float* __restrict__ enc,
    const void* wq, const void* wk, const void* wv,
    unsigned short* q, unsigned short* k, unsigned short* vt,
    const int* __restrict__ flag) {
  __shared__ float xs[2*HID];
  if (*flag) fqkv_body<1>(enc, wq, wk, wv, q, k, vt, xs);
  else       fqkv_body<0>(enc, wq, wk, wv, q, k, vt, xs);
}

// ---------------------------------------------------------------- final attention -> d_out
// 128 blocks (BB*32): 32 queries/block, 4-way key split, 4-wave merge.
__global__ __launch_bounds__(512) void k_fattn(
    const unsigned short* __restrict__ qb, const unsigned short* __restrict__ kb,
    const unsigned short* __restrict__ vtb, void* __restrict__ outp,
    const int* __restrict__ flag) {
  __shared__ unsigned short pl[2][8][16][74];
  __shared__ float accb[8][16][66];
  __shared__ float lb[8][16];
  int tid = threadIdx.x;
  int w = tid >> 6, lane = tid & 63;
  int col = lane & 15, quad = lane >> 4;
  int qt = w >> 2, kh = w & 3;
  int b = blockIdx.x >> 5;
  int n0 = (blockIdx.x & 31) * 32;
  long gbase = (long)b * NN;
  const unsigned short* vrow = vtb + (long)b*HID*NN;

  s8v aq = *(const s8v*)(qb + (gbase + n0 + qt*16 + col)*DKK + quad*8);

  f4v acc[4];
#pragma unroll
  for (int t = 0; t < 4; ++t) acc[t] = (f4v){0.f,0.f,0.f,0.f};
  float psum[4] = {0.f,0.f,0.f,0.f};
  const float rs = 0.17677669529663687f;
  const int cbeg = kh * 256;

#pragma unroll 2
  for (int it = 0; it < 4; ++it) {
    int c0 = cbeg + it*64;
    int pb = it & 1;
    f4v s4[4];
#pragma unroll
    for (int nt = 0; nt < 4; ++nt) {
      s8v bk = *(const s8v*)(kb + (gbase + c0 + nt*16 + col)*DKK + quad*8);
      s4[nt] = __builtin_amdgcn_mfma_f32_16x16x32_bf16(aq, bk,
                (f4v){0.f,0.f,0.f,0.f}, 0, 0, 0);
    }
#pragma unroll
    for (int r = 0; r < 4; ++r) {
      float p0 = expf(s4[0][r]*rs), p1 = expf(s4[1][r]*rs);
      float p2 = expf(s4[2][r]*rs), p3 = expf(s4[3][r]*rs);
      psum[r] += (p0 + p1) + (p2 + p3);
      int row = quad*4 + r;
      pl[pb][w][row][col]      = f2b(p0);
      pl[pb][w][row][16 + col] = f2b(p1);
      pl[pb][w][row][32 + col] = f2b(p2);
      pl[pb][w][row][48 + col] = f2b(p3);
    }
#pragma unroll
    for (int ks = 0; ks < 2; ++ks) {
      s8v ap = *(const s8v*)&pl[pb][w][col][ks*32 + quad*8];
#pragma unroll
      for (int nt = 0; nt < 4; ++nt) {
        s8v bv = *(const s8v*)(vrow + (long)(nt*16 + col)*NN + c0 + ks*32 + quad*8);
        acc[nt] = __builtin_amdgcn_mfma_f32_16x16x32_bf16(ap, bv, acc[nt], 0, 0, 0);
      }
    }
  }

#pragma unroll
  for (int r = 0; r < 4; ++r) {
    float v = psum[r];
#pragma unroll
    for (int off = 1; off < 16; off <<= 1) v += __shfl_xor(v, off);
    psum[r] = v;
  }
#pragma unroll
  for (int t = 0; t < 4; ++t)
#pragma unroll
    for (int r = 0; r < 4; ++r)
      accb[w][quad*4 + r][t*16 + col] = acc[t][r];
  if (col == 0) {
#pragma unroll
    for (int r = 0; r < 4; ++r) lb[w][quad*4 + r] = psum[r];
  }
  __syncthreads();

  int f = *flag;
#pragma unroll
  for (int rr = 0; rr < 4; ++rr) {
    int rl = w*4 + rr;                 // 0..31
    int qtt = rl >> 4, lrr = rl & 15;
    float a = accb[4*qtt][lrr][lane] + accb[4*qtt + 1][lrr][lane]
            + accb[4*qtt + 2][lrr][lane] + accb[4*qtt + 3][lrr][lane];
    float l = lb[4*qtt][lrr] + lb[4*qtt + 1][lrr]
            + lb[4*qtt + 2][lrr] + lb[4*qtt + 3][lrr];
    float val = a / l;
    long idx = (gbase + n0 + rl)*HID + lane;
    if (f) ((float*)outp)[idx] = val;
    else   ((bf16*)outp)[idx] = __float2bfloat16(val);
  }
}

// ================================================================ launch
extern "C" void kernel_launch(void* const* d_in, const int* in_sizes, int n_in,
                              void* d_out, int out_size, void* d_ws, size_t ws_size,
                              hipStream_t stream) {
  static const int EXP[30] = {
    49152, 49152, 384, 128, 49152, 768, 16384, 256,
    524288, 8192, 524288, 256, 256, 256, 256, 256,
    8192, 8192, 16384, 524288, 8192, 524288, 256, 256,
    256, 256, 256, 4096, 4096, 8192
  };
  // z[2] + enc + qb + kb + vt + wcw  (floats)
  const size_t NEED = (size_t)(2*ZS + 524288 + 524288 + 524288 + 1048576 + 1048576) * 4 + 64;
  bool ok = (n_in == 30) && (ws_size >= NEED) && (out_size == BB*NN*HID);
  if (ok) for (int i = 0; i < 30; ++i) ok = ok && (in_sizes[i] == EXP[i]);
  if (!ok) {
    k_zero<<<(BB*NN*HID + 255)/256, 256, 0, stream>>>((unsigned short*)d_out, BB*NN*HID);
    return;
  }

  float* z   = (float*)d_ws;             // 2 × [4,1024,4,64]
  float* enc = z   + 2*ZS;               // [4,1024,128]
  float* qb  = enc + 524288;             // bf16 q [32 groups][1024][32]
  float* kb  = qb  + 524288;             // bf16 k
  float* vb  = kb  + 524288;             // bf16 V^T [32 groups][64][1024]
  float* wcf = vb  + 1048576;            // bf16 FF weights [4 si][4][131072]
  int*  flag = (int*)(wcf + 1048576);
  unsigned short* wcw = (unsigned short*)wcf;

  k_detect<<<1, 256, 0, stream>>>(d_in[0], flag);

  const void *i_traffic=d_in[0], *i_user=d_in[1], *i_pw=d_in[2], *i_pb=d_in[3],
    *i_mw=d_in[4], *i_mb=d_in[5], *i_ow=d_in[6], *i_ob=d_in[7], *i_f1w=d_in[8],
    *i_f1b=d_in[9], *i_f2w=d_in[10], *i_f2b=d_in[11], *i_l1g=d_in[12],
    *i_l1b=d_in[13], *i_l2g=d_in[14], *i_l2b=d_in[15], *i_gwq=d_in[16],
    *i_gwk=d_in[17], *i_gwv=d_in[18], *i_gf1w=d_in[19], *i_gf1b=d_in[20],
    *i_gf2w=d_in[21], *i_gf2b=d_in[22], *i_gl1g=d_in[23], *i_gl1b=d_in[24],
    *i_gl2g=d_in[25], *i_gl2b=d_in[26], *i_cwq=d_in[27], *i_cwk=d_in[28],
    *i_cwv=d_in[29];

  // all 16 FF weight matrices, one dispatch
  k_wconv<<<1024, 256, 0, stream>>>(i_f1w, i_f2w, i_gf1w, i_gf2w, wcw, flag);

  // layer 0: patch -> tattn -> FF -> gqkv, then graph attention
  k_tff<<<512, 256, 0, stream>>>(z,
      i_traffic, i_user, i_pw, i_pb,
      i_mw, i_mb, i_ow, i_ob,
      i_l1g, i_l1b, wcw, 0, i_f1b, i_f2b, i_l2g, i_l2b,
      i_gf1b, i_gf2b, i_gl2g, i_gl2b,
      i_gwq, i_gwk, i_gwv,
      (unsigned short*)qb, (unsigned short*)kb, (unsigned short*)vb, flag);
  k_gattn<<<1024, 512, 0, stream>>>(z,
      (const unsigned short*)qb, (const unsigned short*)kb,
      (const unsigned short*)vb, i_gl1g, i_gl1b, 0, flag);
  // layer 1: gaFF(layer0) -> tattn -> FF -> gqkv, then graph attention
  k_tff<<<512, 256, 0, stream>>>(z,
      i_traffic, i_user, i_pw, i_pb,
      i_mw, i_mb, i_ow, i_ob,
      i_l1g, i_l1b, wcw, 1, i_f1b, i_f2b, i_l2g, i_l2b,
      i_gf1b, i_gf2b, i_gl2g, i_gl2b,
      i_gwq, i_gwk, i_gwv,
      (unsigned short*)qb, (unsigned short*)kb, (unsigned short*)vb, flag);
  k_gattn<<<1024, 512, 0, stream>>>(z,
      (const unsigned short*)qb, (const unsigned short*)kb,
      (const unsigned short*)vb, i_gl1g, i_gl1b, 1, flag);
  // final ga-FF (layer 1) + fused segment-pool
  k_ffmfma<<<512, 256, 0, stream>>>(z, wcw, 1, 2,
      i_gf1b, i_gf2b, i_gl2g, i_gl2b, enc, 1, flag);

  k_fqkv<<<BB*NN, 128, 0, stream>>>(enc, i_cwq, i_cwk, i_cwv,
      (unsigned short*)qb, (unsigned short*)kb, (unsigned short*)vb, flag);
  k_fattn<<<BB*32, 512, 0, stream>>>((const unsigned short*)qb,
      (const unsigned short*)kb, (unsigned short*)vb, d_out, flag);
}

// Round 20
// 561.937 us; speedup vs baseline: 1.0452x; 1.0111x over previous
//
#include <hip/hip_runtime.h>
#include <hip/hip_bf16.h>
#include <math.h>

// Problem constants
#define BB 4
#define SEQL 12
#define NN 1024
#define SEGL 3
#define SEGN 4
#define HID 64
#define FFD 2048
#define DKK 32
#define NHH 8
#define HDD 8
#define ZS 1048576   // floats per z stream [4,1024,4,64]

using bf16 = __hip_bfloat16;
__device__ __forceinline__ float b2f(bf16 v) { return __bfloat162float(v); }

typedef __attribute__((ext_vector_type(8))) short s8v;   // 8 bf16 (4 VGPRs)
typedef __attribute__((ext_vector_type(4))) float f4v;   // MFMA C/D
typedef __attribute__((ext_vector_type(4))) unsigned short u4v;

__device__ __forceinline__ unsigned short f2b(float f) {
  bf16 h = __float2bfloat16(f);
  unsigned short u; __builtin_memcpy(&u, &h, 2); return u;
}
__device__ __forceinline__ float us2f(unsigned short u) {
  unsigned int e = ((unsigned int)u) << 16;
  float f; __builtin_memcpy(&f, &e, 4); return f;
}

// dtype-templated loads: F=1 fp32 storage, F=0 bf16 storage
template <int F>
__device__ __forceinline__ float ldw(const void* p, long i) {
  if (F) return ((const float*)p)[i];
  return b2f(((const bf16*)p)[i]);
}
template <int F>
__device__ __forceinline__ s8v ldfrag(const void* p, long elemOff) {
  if (F) {
    const float* fp = (const float*)p + elemOff;
    f4v u = *(const f4v*)fp, v = *(const f4v*)(fp + 4);
    s8v t;
    t[0]=f2b(u[0]); t[1]=f2b(u[1]); t[2]=f2b(u[2]); t[3]=f2b(u[3]);
    t[4]=f2b(v[0]); t[5]=f2b(v[1]); t[6]=f2b(v[2]); t[7]=f2b(v[3]);
    return t;
  }
  return *(const s8v*)((const unsigned short*)p + elemOff);
}
template <int F>
__device__ __forceinline__ f4v ldb4(const void* p, long i) {  // 4 consecutive vals
  if (F) return *(const f4v*)((const float*)p + i);
  u4v u = *(const u4v*)((const unsigned short*)p + i);
  f4v r; r[0]=us2f(u[0]); r[1]=us2f(u[1]); r[2]=us2f(u[2]); r[3]=us2f(u[3]);
  return r;
}

// ---------------------------------------------------------------- zero-fill d_out (guard path)
__global__ void k_zero(unsigned short* __restrict__ o, int n) {
  int i = blockIdx.x * 256 + threadIdx.x;
  if (i < n) o[i] = 0;
}

// ---------------------------------------------------------------- weight convert, ALL 16 FF mats
// + in-kernel dtype detect (replaces k_detect): every block computes the flag
// locally from the first 1KB of x0 (L2-hot, sub-us); block 0 publishes it for
// all subsequent dispatches (stream order guarantees visibility).
// layout: [si 0..3][which 0..3][131072], which: 0=ff1 1=ff2 2=ga_ff1 3=ga_ff2
template <int F>
__device__ __forceinline__ void wconv_body(const void* __restrict__ w1,
    const void* __restrict__ w2, const void* __restrict__ w3,
    const void* __restrict__ w4, unsigned short* __restrict__ out) {
  int i = blockIdx.x * 256 + threadIdx.x;
  long e8 = (long)i * 8;
  int slot = (int)(e8 >> 17);       // 0..15
  int si = slot >> 2, which = slot & 3;
  long r = e8 & 131071;
  const void* src = (which == 0) ? w1 : (which == 1) ? w2 : (which == 2) ? w3 : w4;
  *(s8v*)(out + e8) = ldfrag<F>(src, (long)si*FFD*HID + r);
}
__global__ __launch_bounds__(256) void k_wconv(const void* w1, const void* w2,
    const void* w3, const void* w4, unsigned short* out,
    const void* __restrict__ x0, int* __restrict__ flag) {
  __shared__ int tot;
  int t = threadIdx.x;
  int bad = 0;
  const bf16* p = (const bf16*)x0;
  for (int i = t; i < 512; i += 256) {
    float a = fabsf(b2f(p[i]));
    if (!(a < 1e4f) || (a != 0.f && a < 1e-4f)) bad = 1;
  }
  if (t == 0) tot = 0;
  __syncthreads();
  unsigned long long m = __ballot(bad);
  if ((t & 63) == 0) atomicAdd(&tot, __popcll(m));
  __syncthreads();
  int f = (tot > 64) ? 1 : 0;       // 1 = fp32 storage, 0 = bf16
  if (blockIdx.x == 0 && t == 0) *flag = f;
  if (f) wconv_body<1>(w1, w2, w3, w4, out);
  else   wconv_body<0>(w1, w2, w3, w4, out);
}

// ---------------------------------------------------------------- FF staging helpers (v11)
#define TT 64
#define FRW 64
#define HCS 74

__device__ __forceinline__ void ff_ld(const unsigned short* __restrict__ wc1,
    const unsigned short* __restrict__ wc2, int hb, int srow, int le,
    s8v* r1, s8v* r2) {
  r1[0] = *(const s8v*)(wc1 + (long)(hb + srow)*HID + le*8);
  r1[1] = *(const s8v*)(wc1 + (long)(hb + srow + 8)*HID + le*8);
  r2[0] = *(const s8v*)(wc2 + (long)srow*FFD + hb + le*8);
  r2[1] = *(const s8v*)(wc2 + (long)(srow + 8)*FFD + hb + le*8);
}
__device__ __forceinline__ void ff_wr(char* ldsbuf, int pb, int srow, int swb,
    const s8v* r1, const s8v* r2) {
  char* w1b = ldsbuf + pb*8192;
  char* w2b = ldsbuf + 16384 + pb*8192;
  *(s8v*)(w1b + srow*128 + swb) = r1[0];
  *(s8v*)(w1b + (srow + 8)*128 + swb) = r1[1];
  *(s8v*)(w2b + srow*128 + swb) = r2[0];
  *(s8v*)(w2b + (srow + 8)*128 + swb) = r2[1];
}
// one 64-h compute step: FF1 tile -> ReLU -> hcw; FF2 partial into acc
template <int F>
__device__ __forceinline__ void ff_compute(const char* ldsbuf, int pb, int hb,
    int col, int quad, int sw, const s8v* bx, unsigned short* hcw,
    const void* __restrict__ B1, long ob1, f4v* acc) {
  const char* w1b = ldsbuf + pb*8192;
  const char* w2b = ldsbuf + 16384 + pb*8192;
#pragma unroll
  for (int t = 0; t < 4; ++t) {
    int row = t*16 + col;
    s8v a10 = *(const s8v*)(w1b + row*128 + ((quad*16) ^ sw));
    s8v a11 = *(const s8v*)(w1b + row*128 + ((64 + quad*16) ^ sw));
    f4v bv = ldb4<F>(B1, ob1 + hb + t*16 + quad*4);
    f4v sv = __builtin_amdgcn_mfma_f32_16x16x32_bf16(a10, bx[0],
               (f4v){0.f,0.f,0.f,0.f}, 0, 0, 0);
    sv = __builtin_amdgcn_mfma_f32_16x16x32_bf16(a11, bx[1], sv, 0, 0, 0);
    unsigned short pk[4];
#pragma unroll
    for (int r = 0; r < 4; ++r) pk[r] = f2b(fmaxf(sv[r] + bv[r], 0.f));
    *(unsigned long long*)&hcw[col*HCS + t*16 + quad*4] =
      (unsigned long long)pk[0] | ((unsigned long long)pk[1] << 16) |
      ((unsigned long long)pk[2] << 32) | ((unsigned long long)pk[3] << 48);
  }
#pragma unroll
  for (int ks2 = 0; ks2 < 2; ++ks2) {
    s8v bh = *(const s8v*)&hcw[col*HCS + ks2*32 + quad*8];
#pragma unroll
    for (int m = 0; m < 4; ++m) {
      int r2 = m*16 + col;
      s8v a2 = *(const s8v*)(w2b + r2*128 + ((ks2*64 + quad*16) ^ sw));
      acc[m] = __builtin_amdgcn_mfma_f32_16x16x32_bf16(a2, bh, acc[m], 0, 0, 0);
    }
  }
}
// full 32-step depth-2-pipelined FF pass (acc accumulates FF2 partials)
template <int F>
__device__ __forceinline__ void ff_run(char* ldsbuf,
    const unsigned short* __restrict__ wc1, const unsigned short* __restrict__ wc2,
    const void* __restrict__ B1, long ob1, const s8v* bx, unsigned short* hcw,
    int col, int quad, int sw, int srow, int le, int swb, f4v* acc) {
  s8v c1[2], c2[2], rA1[2], rA2[2], rB1[2], rB2[2];
  ff_ld(wc1, wc2, 0, srow, le, c1, c2);
  ff_wr(ldsbuf, 0, srow, swb, c1, c2);
  ff_ld(wc1, wc2, 64, srow, le, rA1, rA2);
  ff_ld(wc1, wc2, 128, srow, le, rB1, rB2);
  __syncthreads();
  for (int c = 0; c < 32; c += 2) {
    ff_compute<F>(ldsbuf, 0, c*64, col, quad, sw, bx, hcw, B1, ob1, acc);
    ff_wr(ldsbuf, 1, srow, swb, rA1, rA2);
    if (c + 3 < 32) ff_ld(wc1, wc2, (c+3)*64, srow, le, rA1, rA2);
    __syncthreads();
    ff_compute<F>(ldsbuf, 1, (c+1)*64, col, quad, sw, bx, hcw, B1, ob1, acc);
    if (c + 2 < 32) ff_wr(ldsbuf, 0, srow, swb, rB1, rB2);
    if (c + 4 < 32) ff_ld(wc1, wc2, (c+4)*64, srow, le, rB1, rB2);
    __syncthreads();
  }
}

// ---------------------------------------------------------------- FUSED {patch | gaFF(prev)} + temporal attn + FF + graph qkv (k_tff)
template <int F>
__device__ __forceinline__ void tff_body(float* __restrict__ zb,
    const void* __restrict__ xt, const void* __restrict__ xu,
    const void* __restrict__ pw, const void* __restrict__ pbp,
    const void* __restrict__ W, const void* __restrict__ bq,
    const void* __restrict__ WO, const void* __restrict__ bo,
    const void* __restrict__ g1, const void* __restrict__ b1,
    const unsigned short* __restrict__ wcw, int li,
    const void* __restrict__ B1, const void* __restrict__ B2,
    const void* __restrict__ G, const void* __restrict__ Bt,
    const void* __restrict__ pgf1b, const void* __restrict__ pgf2b,
    const void* __restrict__ pgl2g, const void* __restrict__ pgl2b,
    const void* __restrict__ gwq, const void* __restrict__ gwk,
    const void* __restrict__ gwv,
    unsigned short* __restrict__ qo, unsigned short* __restrict__ ko,
    unsigned short* __restrict__ vto,
    char* lds) {
  int s = blockIdx.x >> 8, blk = blockIdx.x & 255;
  long si = s*2 + li;
  float* z = zb + (long)s*ZS;
  long oW = si*3*HID*HID, obq = si*3*HID, oWO = si*HID*HID, obo = si*HID;
  long og1 = si*HID, ob1 = si*HID;
  const unsigned short* wc1 = wcw + (si*4 + 0)*131072;
  const unsigned short* wc2 = wcw + (si*4 + 1)*131072;
  long fob1 = si*FFD, fob2 = si*HID, fog = si*HID, fobt = si*HID;
  unsigned short (*qkvs)[200] = (unsigned short(*)[200])lds;        // 25600 B
  unsigned short (*ao)[72]    = (unsigned short(*)[72])(lds + 25600); // 9216 B
  float (*yb)[68]             = (float(*)[68])(lds + 34816);          // 17408 B
  int tid = threadIdx.x;
  int w = tid >> 6, lane = tid & 63;
  int col = lane & 15, quad = lane >> 4;
  long r0 = (long)blk * TT;
  float* stash = (float*)(lds + 59648);             // [64][68] block-wide
  float* stashW = stash + w*16*68;                  // wave's rows
  unsigned short* hcw = (unsigned short*)(lds + 32768 + w*2368);  // [16][74]
  float* red = (float*)(lds + 42240 + w*4352);                    // [16][68]
  int lr = lane >> 3, le = lane & 7;
  int srow = w*16 + lr;
  int swb = ((le ^ lr) << 4);
  const int sw = (col & 7) << 4;

  if (li == 0) {
    // ================= phase 0: patch embed -> stash =================
    const void* x = s ? xu : xt;
    long opw = (long)s*HID*SEGL, opb = (long)s*HID;
    float dv = expf((float)(2*(lane >> 1)) * (-logf(10000.f) / (float)HID));
    float pe[4];
#pragma unroll
    for (int g = 0; g < 4; ++g) {
      float ang = (float)g * dv;
      pe[g] = (lane & 1) ? cosf(ang) : sinf(ang);
    }
    float pbv = ldw<F>(pbp, opb + lane);
    float pwv[3];
#pragma unroll
    for (int l = 0; l < 3; ++l) pwv[l] = ldw<F>(pw, opw + lane*3 + l);
#pragma unroll
    for (int rr = 0; rr < 16; ++rr) {
      long tok = r0 + w*16 + rr;
      int b_ = (int)(tok >> 12);
      int n_ = (int)((tok >> 2) & 1023);
      int g_ = (int)(tok & 3);
      float a = pbv;
#pragma unroll
      for (int l = 0; l < 3; ++l)
        a += ldw<F>(x, (long)(b_*SEQL + g_*SEGL + l)*NN + n_) * pwv[l];
      stashW[rr*68 + lane] = a + pe[g_];
    }
    __syncthreads();
  } else {
    // ================= phase -1: gaFF of layer 0 -> stash =================
    long sip = s*2;                    // prev layer (li==0) slot
    const unsigned short* pw1 = wcw + (sip*4 + 2)*131072;
    const unsigned short* pw2 = wcw + (sip*4 + 3)*131072;
    long pob1 = sip*FFD, pob2 = sip*HID, pog = sip*HID, pobt = sip*HID;
    s8v bxp[2];
    {
      const float* xr = z + (r0 + w*16 + col) * HID;
#pragma unroll
      for (int ks = 0; ks < 2; ++ks) {
        const float* p = xr + ks*32 + quad*8;
        f4v u = *(const f4v*)p, v = *(const f4v*)(p + 4);
        s8v t;
        t[0]=f2b(u[0]); t[1]=f2b(u[1]); t[2]=f2b(u[2]); t[3]=f2b(u[3]);
        t[4]=f2b(v[0]); t[5]=f2b(v[1]); t[6]=f2b(v[2]); t[7]=f2b(v[3]);
        bxp[ks] = t;
      }
    }
    f4v accp[4];
#pragma unroll
    for (int m = 0; m < 4; ++m) accp[m] = (f4v){0.f,0.f,0.f,0.f};
    ff_run<F>(lds, pw1, pw2, pgf1b, pob1, bxp, hcw, col, quad, sw, srow, le, swb, accp);
#pragma unroll
    for (int m = 0; m < 4; ++m)
      *(f4v*)&red[col*68 + m*16 + quad*4] = accp[m];
    float pgg = ldw<F>(pgl2g, pog + lane), pbb = ldw<F>(pgl2b, pobt + lane);
    float pb2 = ldw<F>(pgf2b, pob2 + lane);
#pragma unroll
    for (int rr = 0; rr < 16; ++rr) {
      long grow = r0 + w*16 + rr;
      float val = red[rr*68 + lane] + pb2 + z[grow*HID + lane];
      float sm = val;
#pragma unroll
      for (int off = 32; off; off >>= 1) sm += __shfl_xor(sm, off);
      float m = sm * (1.f/HID);
      float d = val - m;
      float sq = d*d;
#pragma unroll
      for (int off = 32; off; off >>= 1) sq += __shfl_xor(sq, off);
      float rv = rsqrtf(sq*(1.f/HID) + 1e-5f);
      stashW[rr*68 + lane] = d*rv*pgg + pbb;
    }
    __syncthreads();
  }

  // ================= phase 1: temporal attention (input from stash) =================
  s8v bx[4][2];
#pragma unroll
  for (int mt = 0; mt < 4; ++mt) {
    const float* xr = &stash[(mt*16 + col)*68];
#pragma unroll
    for (int ks = 0; ks < 2; ++ks) {
      const float* p = xr + ks*32 + quad*8;
      f4v u = *(const f4v*)p, v = *(const f4v*)(p + 4);
      s8v t;
      t[0]=f2b(u[0]); t[1]=f2b(u[1]); t[2]=f2b(u[2]); t[3]=f2b(u[3]);
      t[4]=f2b(v[0]); t[5]=f2b(v[1]); t[6]=f2b(v[2]); t[7]=f2b(v[3]);
      bx[mt][ks] = t;
    }
  }
#pragma unroll
  for (int nt = 0; nt < 3; ++nt) {
    int cbase = (w*3 + nt) * 16;
    s8v aw[2];
#pragma unroll
    for (int ks = 0; ks < 2; ++ks)
      aw[ks] = ldfrag<F>(W, oW + (long)(cbase + col)*HID + ks*32 + quad*8);
    f4v bv = ldb4<F>(bq, obq + cbase + quad*4);
#pragma unroll
    for (int mt = 0; mt < 4; ++mt) {
      f4v sv = (f4v){0.f,0.f,0.f,0.f};
#pragma unroll
      for (int ks = 0; ks < 2; ++ks)
        sv = __builtin_amdgcn_mfma_f32_16x16x32_bf16(aw[ks], bx[mt][ks], sv, 0, 0, 0);
      unsigned short pk[4];
#pragma unroll
      for (int r = 0; r < 4; ++r) pk[r] = f2b(sv[r] + bv[r]);
      *(unsigned long long*)&qkvs[mt*16 + col][cbase + quad*4] =
        (unsigned long long)pk[0] | ((unsigned long long)pk[1] << 16) |
        ((unsigned long long)pk[2] << 32) | ((unsigned long long)pk[3] << 48);
    }
  }
  __syncthreads();
  if (tid < 128) {
    int gi = tid >> 3, hd = tid & 7;
    int tl = gi * 4;
    float qv[4][8], kv[4][8], vv[4][8];
#pragma unroll
    for (int t4 = 0; t4 < 4; ++t4) {
      s8v qq = *(const s8v*)&qkvs[tl + t4][hd*8];
      s8v kk = *(const s8v*)&qkvs[tl + t4][64 + hd*8];
      s8v vq = *(const s8v*)&qkvs[tl + t4][128 + hd*8];
#pragma unroll
      for (int e = 0; e < 8; ++e) {
        qv[t4][e] = us2f((unsigned short)qq[e]);
        kv[t4][e] = us2f((unsigned short)kk[e]);
        vv[t4][e] = us2f((unsigned short)vq[e]);
      }
    }
    const float sc8 = 0.3535533905932738f;   // 1/sqrt(8)
#pragma unroll
    for (int qt = 0; qt < 4; ++qt) {
      float sc[4]; float mx = -1e30f;
#pragma unroll
      for (int kt = 0; kt < 4; ++kt) {
        float d = 0;
#pragma unroll
        for (int e = 0; e < 8; ++e) d += qv[qt][e]*kv[kt][e];
        sc[kt] = d*sc8; mx = fmaxf(mx, sc[kt]);
      }
      float se = 0;
#pragma unroll
      for (int kt = 0; kt < 4; ++kt) { sc[kt] = expf(sc[kt]-mx); se += sc[kt]; }
      float inv = 1.f/se;
      s8v outp;
#pragma unroll
      for (int e = 0; e < 8; ++e) {
        float o = 0;
#pragma unroll
        for (int kt = 0; kt < 4; ++kt) o += sc[kt]*vv[kt][e];
        outp[e] = (short)f2b(o*inv);
      }
      *(s8v*)&ao[tl + qt][hd*8] = outp;
    }
  }
  __syncthreads();
  s8v awo[2];
#pragma unroll
  for (int ks = 0; ks < 2; ++ks)
    awo[ks] = ldfrag<F>(WO, oWO + (long)(w*16 + col)*HID + ks*32 + quad*8);
  f4v bov = ldb4<F>(bo, obo + w*16 + quad*4);
#pragma unroll
  for (int mt = 0; mt < 4; ++mt) {
    f4v ov = (f4v){0.f,0.f,0.f,0.f};
#pragma unroll
    for (int ks = 0; ks < 2; ++ks) {
      s8v bao = *(const s8v*)&ao[mt*16 + col][ks*32 + quad*8];
      ov = __builtin_amdgcn_mfma_f32_16x16x32_bf16(awo[ks], bao, ov, 0, 0, 0);
    }
    f4v yv;
#pragma unroll
    for (int r = 0; r < 4; ++r) yv[r] = ov[r] + bov[r];
    *(f4v*)&yb[mt*16 + col][w*16 + quad*4] = yv;
  }
  __syncthreads();
  {
    float gg = ldw<F>(g1, og1 + lane), bb2 = ldw<F>(b1, ob1 + lane);
#pragma unroll
    for (int rr = 0; rr < 16; ++rr) {
      int row = w*16 + rr;
      float val = yb[row][lane] + stashW[rr*68 + lane];
      float sm = val;
#pragma unroll
      for (int off = 32; off; off >>= 1) sm += __shfl_xor(sm, off);
      float m = sm*(1.f/HID);
      float d = val - m, sq = d*d;
#pragma unroll
      for (int off = 32; off; off >>= 1) sq += __shfl_xor(sq, off);
      float rv = rsqrtf(sq*(1.f/HID) + 1e-5f);
      stashW[rr*68 + lane] = d*rv*gg + bb2;     // LN1 -> stash (in-place safe)
    }
  }
  __syncthreads();   // attn LDS dead; FF regions may now be written

  // ================= phase 2: FF (depth-2 pipeline) =================
  s8v bx2[2];
#pragma unroll
  for (int ks = 0; ks < 2; ++ks) {
    const float* p = &stashW[col*68 + ks*32 + quad*8];
    f4v u = *(const f4v*)p, v = *(const f4v*)(p + 4);
    s8v t;
    t[0]=f2b(u[0]); t[1]=f2b(u[1]); t[2]=f2b(u[2]); t[3]=f2b(u[3]);
    t[4]=f2b(v[0]); t[5]=f2b(v[1]); t[6]=f2b(v[2]); t[7]=f2b(v[3]);
    bx2[ks] = t;
  }

  f4v acc[4];
#pragma unroll
  for (int m = 0; m < 4; ++m) acc[m] = (f4v){0.f,0.f,0.f,0.f};
  ff_run<F>(lds, wc1, wc2, B1, fob1, bx2, hcw, col, quad, sw, srow, le, swb, acc);

#pragma unroll
  for (int m = 0; m < 4; ++m)
    *(f4v*)&red[col*68 + m*16 + quad*4] = acc[m];
  float* finb = (float*)lds;     // [64][68], overlays wdbuf (dead after loop)
  {
    float fgg = ldw<F>(G, fog + lane), fbbt = ldw<F>(Bt, fobt + lane);
    float b2v = ldw<F>(B2, fob2 + lane);
#pragma unroll
    for (int rr = 0; rr < 16; ++rr) {
      long grow = r0 + w*16 + rr;
      float val = red[rr*68 + lane] + b2v + stashW[rr*68 + lane];
      float sm = val;
#pragma unroll
      for (int off = 32; off; off >>= 1) sm += __shfl_xor(sm, off);
      float m = sm * (1.f/HID);
      float d = val - m;
      float sq = d*d;
#pragma unroll
      for (int off = 32; off; off >>= 1) sq += __shfl_xor(sq, off);
      float rv = rsqrtf(sq*(1.f/HID) + 1e-5f);
      float fin = d*rv*fgg + fbbt;
      z[grow*HID + lane] = fin;
      finb[(w*16 + rr)*68 + lane] = fin;
    }
  }
  __syncthreads();   // finb visible block-wide

  // ================= phase 3: fused graph qkv =================
  long oq = si*DKK*HID, okk = si*DKK*HID, ovv = si*HID*HID;
  s8v bx3[4][2];
#pragma unroll
  for (int rt = 0; rt < 4; ++rt)
#pragma unroll
    for (int ks = 0; ks < 2; ++ks) {
      const float* p = &finb[(rt*16 + col)*68 + ks*32 + quad*8];
      f4v u = *(const f4v*)p, v = *(const f4v*)(p + 4);
      s8v t;
      t[0]=f2b(u[0]); t[1]=f2b(u[1]); t[2]=f2b(u[2]); t[3]=f2b(u[3]);
      t[4]=f2b(v[0]); t[5]=f2b(v[1]); t[6]=f2b(v[2]); t[7]=f2b(v[3]);
      bx3[rt][ks] = t;
    }
#pragma unroll
  for (int tt = 0; tt < 2; ++tt) {
    int ct = w*2 + tt;                        // wave-uniform
    const void* wp; long wo; int co; int kind; // 0=q,1=k,2=v
    if (ct < 2)      { wp = gwq; wo = oq;  co = ct*16;      kind = 0; }
    else if (ct < 4) { wp = gwk; wo = okk; co = (ct-2)*16;  kind = 1; }
    else             { wp = gwv; wo = ovv; co = (ct-4)*16;  kind = 2; }
    s8v aw[2];
#pragma unroll
    for (int ks = 0; ks < 2; ++ks)
      aw[ks] = ldfrag<F>(wp, wo + (long)(co + col)*HID + ks*32 + quad*8);
#pragma unroll
    for (int rt = 0; rt < 4; ++rt) {
      f4v sv = (f4v){0.f,0.f,0.f,0.f};
#pragma unroll
      for (int ks = 0; ks < 2; ++ks)
        sv = __builtin_amdgcn_mfma_f32_16x16x32_bf16(aw[ks], bx3[rt][ks], sv, 0, 0, 0);
      long tok2 = r0 + rt*16 + col;
      int b_ = (int)(tok2 >> 12);
      int n_ = (int)((tok2 >> 2) & 1023);
      int g_ = (int)(tok2 & 3);
      int sgl = s*16 + b_*4 + g_;
      if (kind == 2) {
        long vbase = (long)sgl*HID*NN;
#pragma unroll
        for (int r = 0; r < 4; ++r)
          vto[vbase + (long)(co + quad*4 + r)*NN + n_] = f2b(sv[r]);
      } else {
        long row = (long)sgl*NN + n_;
        unsigned short pk[4];
#pragma unroll
        for (int r = 0; r < 4; ++r) pk[r] = f2b(sv[r]);
        unsigned short* dst = kind ? ko : qo;
        *(unsigned long long*)&dst[row*DKK + co + quad*4] =
          (unsigned long long)pk[0] | ((unsigned long long)pk[1] << 16) |
          ((unsigned long long)pk[2] << 32) | ((unsigned long long)pk[3] << 48);
      }
    }
  }
}
__global__ __launch_bounds__(256) void k_tff(float* __restrict__ z,
    const void* xt, const void* xu, const void* pw, const void* pbp,
    const void* W, const void* bqkv, const void* WO, const void* bo,
    const void* g1, const void* b1,
    const unsigned short* __restrict__ wcw, int li,
    const void* B1, const void* B2, const void* G, const void* Bt,
    const void* pgf1b, const void* pgf2b, const void* pgl2g, const void* pgl2b,
    const void* gwq, const void* gwk, const void* gwv,
    unsigned short* qo, unsigned short* ko, unsigned short* vto,
    const int* __restrict__ flag) {
  __shared__ __attribute__((aligned(16))) char lds[77056];
  if (*flag) tff_body<1>(z, xt, xu, pw, pbp, W, bqkv, WO, bo, g1, b1, wcw, li,
                         B1, B2, G, Bt, pgf1b, pgf2b, pgl2g, pgl2b,
                         gwq, gwk, gwv, qo, ko, vto, lds);
  else       tff_body<0>(z, xt, xu, pw, pbp, W, bqkv, WO, bo, g1, b1, wcw, li,
                         B1, B2, G, Bt, pgf1b, pgf2b, pgl2g, pgl2b,
                         gwq, gwk, gwv, qo, ko, vto, lds);
}

// ---------------------------------------------------------------- FF via MFMA bf16 (v11 + fused pool)
template <int F>
__device__ __forceinline__ void ffmfma_body(float* __restrict__ xb,
    const unsigned short* __restrict__ wcw, int li, int wsel,
    const void* __restrict__ B1, const void* __restrict__ B2,
    const void* __restrict__ G, const void* __restrict__ Bt,
    float* __restrict__ enc, int dop,
    char* ldsbuf) {
  int s = blockIdx.x >> 8, blk = blockIdx.x & 255;
  long si = s*2 + li;
  float* x = xb + (long)s*ZS;
  const unsigned short* wc1 = wcw + (si*4 + wsel)*131072;
  const unsigned short* wc2 = wcw + (si*4 + wsel + 1)*131072;
  long ob1 = si*FFD, ob2 = si*HID, og = si*HID, obt = si*HID;
  int tid = threadIdx.x;
  int w = tid >> 6, lane = tid & 63;
  int col = lane & 15, quad = lane >> 4;
  long r0 = (long)blk * FRW;
  unsigned short* hcw = (unsigned short*)(ldsbuf + 32768 + w*2368);  // [16 tok][74]
  float* red = (float*)(ldsbuf + w*4352);   // overlays wdbuf; used after final barrier

  long tokc = r0 + w*16 + col;
  s8v bx[2];
  {
    const float* xr = x + tokc * HID;
#pragma unroll
    for (int ks = 0; ks < 2; ++ks) {
      const float* p = xr + ks*32 + quad*8;
      f4v u = *(const f4v*)p, v = *(const f4v*)(p + 4);
      s8v t;
      t[0]=f2b(u[0]); t[1]=f2b(u[1]); t[2]=f2b(u[2]); t[3]=f2b(u[3]);
      t[4]=f2b(v[0]); t[5]=f2b(v[1]); t[6]=f2b(v[2]); t[7]=f2b(v[3]);
      bx[ks] = t;
    }
  }

  int lr = lane >> 3;
  int le = lane & 7;
  int srow = w*16 + lr;
  int swb = ((le ^ lr) << 4);
  const int sw = (col & 7) << 4;

  f4v acc[4];
#pragma unroll
  for (int m = 0; m < 4; ++m) acc[m] = (f4v){0.f,0.f,0.f,0.f};
  ff_run<F>(ldsbuf, wc1, wc2, B1, ob1, bx, hcw, col, quad, sw, srow, le, swb, acc);

#pragma unroll
  for (int m = 0; m < 4; ++m)
    *(f4v*)&red[col*68 + m*16 + quad*4] = acc[m];
  float gg = ldw<F>(G, og + lane), bbt = ldw<F>(Bt, obt + lane);
  float b2v = ldw<F>(B2, ob2 + lane);
  float pacc[4] = {0.f,0.f,0.f,0.f};
#pragma unroll
  for (int rr = 0; rr < 16; ++rr) {
    long grow = r0 + w*16 + rr;
    float val = red[rr*68 + lane] + b2v + x[grow*HID + lane];
    float sm = val;
#pragma unroll
    for (int off = 32; off; off >>= 1) sm += __shfl_xor(sm, off);
    float m = sm * (1.f/HID);
    float d = val - m;
    float sq = d*d;
#pragma unroll
    for (int off = 32; off; off >>= 1) sq += __shfl_xor(sq, off);
    float rv = rsqrtf(sq*(1.f/HID) + 1e-5f);
    float fin = d*rv*gg + bbt;
    x[grow*HID + lane] = fin;
    pacc[rr >> 2] += fin;
  }
  if (dop) {           // fused segment-pool: this tile = 16 whole nodes
#pragma unroll
    for (int j = 0; j < 4; ++j) {
      long tok = r0 + w*16 + j*4;
      enc[(tok >> 2)*(2*HID) + s*HID + lane] = pacc[j]*0.25f;
    }
  }
}
__global__ __launch_bounds__(256) void k_ffmfma(float* __restrict__ x,
    const unsigned short* __restrict__ wcw, int li, int wsel,
    const void* B1, const void* B2, const void* G, const void* Bt,
    float* enc, int dop, const int* __restrict__ flag) {
  __shared__ __attribute__((aligned(16))) char ldsbuf[42240];
  if (*flag) ffmfma_body<1>(x, wcw, li, wsel, B1, B2, G, Bt, enc, dop, ldsbuf);
  else       ffmfma_body<0>(x, wcw, li, wsel, B1, B2, G, Bt, enc, dop, ldsbuf);
}

// ---------------------------------------------------------------- graph attention (dual-s, 4-way key split)
// 1024 blocks: 32 queries/block, 4-way key split (kh=w&3, 256 keys each),
// 4-wave merge in LDS (no max state -> partial accs and sums just add).
__global__ __launch_bounds__(512) void k_gattn(float* __restrict__ zb,
    const unsigned short* __restrict__ qb, const unsigned short* __restrict__ kb,
    const unsigned short* __restrict__ vtb,
    const void* __restrict__ g1, const void* __restrict__ b1, int li,
    const int* __restrict__ flag) {
  int f = *flag;
  __shared__ unsigned short pl[2][8][16][74];  // ping-pong, wave-private, 74-pad
  __shared__ float accb[8][16][66];
  __shared__ float lb[8][16];
  int tid = threadIdx.x;
  int w = tid >> 6, lane = tid & 63;
  int col = lane & 15, quad = lane >> 4;
  int qt = w >> 2, kh = w & 3;
  int sg = blockIdx.x >> 5;              // 0..31
  int s = sg >> 4, bg = sg & 15;
  int n0 = (blockIdx.x & 31) * 32;
  long si = s*2 + li;
  float* z = zb + (long)s*ZS;
  long og1 = si*HID, ob1 = si*HID;
  long gbase = (long)sg * NN;
  const unsigned short* vrow = vtb + (long)sg*HID*NN;

  s8v aq = *(const s8v*)(qb + (gbase + n0 + qt*16 + col)*DKK + quad*8);

  f4v acc[4];
#pragma unroll
  for (int t = 0; t < 4; ++t) acc[t] = (f4v){0.f,0.f,0.f,0.f};
  float psum[4] = {0.f,0.f,0.f,0.f};
  const float rs = 0.17677669529663687f;   // 1/sqrt(32)
  const int cbeg = kh * 256;

#pragma unroll 2
  for (int it = 0; it < 4; ++it) {
    int c0 = cbeg + it*64;
    int pb = it & 1;
    f4v s4[4];
#pragma unroll
    for (int nt = 0; nt < 4; ++nt) {
      s8v bk = *(const s8v*)(kb + (gbase + c0 + nt*16 + col)*DKK + quad*8);
      s4[nt] = __builtin_amdgcn_mfma_f32_16x16x32_bf16(aq, bk,
                (f4v){0.f,0.f,0.f,0.f}, 0, 0, 0);
    }
#pragma unroll
    for (int r = 0; r < 4; ++r) {
      float p0 = expf(s4[0][r]*rs), p1 = expf(s4[1][r]*rs);
      float p2 = expf(s4[2][r]*rs), p3 = expf(s4[3][r]*rs);
      psum[r] += (p0 + p1) + (p2 + p3);
      int row = quad*4 + r;
      pl[pb][w][row][col]      = f2b(p0);
      pl[pb][w][row][16 + col] = f2b(p1);
      pl[pb][w][row][32 + col] = f2b(p2);
      pl[pb][w][row][48 + col] = f2b(p3);
    }
#pragma unroll
    for (int ks = 0; ks < 2; ++ks) {
      s8v ap = *(const s8v*)&pl[pb][w][col][ks*32 + quad*8];
#pragma unroll
      for (int nt = 0; nt < 4; ++nt) {
        s8v bv = *(const s8v*)(vrow + (long)(nt*16 + col)*NN + c0 + ks*32 + quad*8);
        acc[nt] = __builtin_amdgcn_mfma_f32_16x16x32_bf16(ap, bv, acc[nt], 0, 0, 0);
      }
    }
  }

#pragma unroll
  for (int r = 0; r < 4; ++r) {
    float v = psum[r];
#pragma unroll
    for (int off = 1; off < 16; off <<= 1) v += __shfl_xor(v, off);
    psum[r] = v;
  }
#pragma unroll
  for (int t = 0; t < 4; ++t)
#pragma unroll
    for (int r = 0; r < 4; ++r)
      accb[w][quad*4 + r][t*16 + col] = acc[t][r];
  if (col == 0) {
#pragma unroll
    for (int r = 0; r < 4; ++r) lb[w][quad*4 + r] = psum[r];
  }
  __syncthreads();

  int b = bg >> 2, g = bg & 3;
  float gg = f ? ((const float*)g1)[og1 + lane] : b2f(((const bf16*)g1)[og1 + lane]);
  float bb = f ? ((const float*)b1)[ob1 + lane] : b2f(((const bf16*)b1)[ob1 + lane]);
#pragma unroll
  for (int rr = 0; rr < 4; ++rr) {
    int rl = w*4 + rr;                 // 0..31
    int qtt = rl >> 4, lrr = rl & 15;
    float a = accb[4*qtt][lrr][lane] + accb[4*qtt + 1][lrr][lane]
            + accb[4*qtt + 2][lrr][lane] + accb[4*qtt + 3][lrr][lane];
    float l = lb[4*qtt][lrr] + lb[4*qtt + 1][lrr]
            + lb[4*qtt + 2][lrr] + lb[4*qtt + 3][lrr];
    float val = a / l;
    float s2 = val;
#pragma unroll
    for (int off = 32; off; off >>= 1) s2 += __shfl_xor(s2, off);
    float m = s2*(1.f/HID);
    float d = val - m, sq = d*d;
#pragma unroll
    for (int off = 32; off; off >>= 1) sq += __shfl_xor(sq, off);
    float r = rsqrtf(sq*(1.f/HID) + 1e-5f);
    float* zp = z + ((long)(b*NN + n0 + rl)*SEGN + g)*HID;
    zp[lane] = d*r*gg + bb + zp[lane];   // LN(att) + x
  }
}

// ---------------------------------------------------------------- final qkv proj (in_dim=128)
// v emitted as bf16 V^T: vt[b][dim 0..63][key 0..1023]
template <int F>
__device__ __forceinline__ void fqkv_body(const float* __restrict__ enc,
    const void* __restrict__ wq, const void* __restrict__ wk,
    const void* __restrict__ wv,
    unsigned short* __restrict__ q, unsigned short* __restrict__ k,
    unsigned short* __restrict__ vt, float* xs) {
  long r = blockIdx.x;
  int t = threadIdx.x;
  xs[t] = enc[r*128 + t];
  __syncthreads();
  if (t < 32) {
    long wr = (long)t*128; float a = 0;
    for (int e = 0; e < 128; ++e) a += xs[e]*ldw<F>(wq, wr + e);
    q[r*DKK + t] = f2b(a);
  } else if (t < 64) {
    long wr = (long)(t-32)*128; float a = 0;
    for (int e = 0; e < 128; ++e) a += xs[e]*ldw<F>(wk, wr + e);
    k[r*DKK + (t-32)] = f2b(a);
  } else {
    long wr = (long)(t-64)*128; float a = 0;
    for (int e = 0; e < 128; ++e) a += xs[e]*ldw<F>(wv, wr + e);
    vt[((r >> 10)*HID + (t-64))*NN + (r & 1023)] = f2b(a);
  }
}
__global__ __launch_bounds__(128) void k_fqkv(const float* __restrict__ enc,
    const void* wq, const void* wk, const void* wv,
    unsigned short* q, unsigned short* k, unsigned short* vt,
    const int* __restrict__ flag) {
  __shared__ float xs[2*HID];
  if (*flag) fqkv_body<1>(enc, wq, wk, wv, q, k, vt, xs);
  else       fqkv_body<0>(enc, wq, wk, wv, q, k, vt, xs);
}

// ---------------------------------------------------------------- final attention -> d_out
// 128 blocks (BB*32): 32 queries/block, 4-way key split, 4-wave merge.
__global__ __launch_bounds__(512) void k_fattn(
    const unsigned short* __restrict__ qb, const unsigned short* __restrict__ kb,
    const unsigned short* __restrict__ vtb, void* __restrict__ outp,
    const int* __restrict__ flag) {
  __shared__ unsigned short pl[2][8][16][74];
  __shared__ float accb[8][16][66];
  __shared__ float lb[8][16];
  int tid = threadIdx.x;
  int w = tid >> 6, lane = tid & 63;
  int col = lane & 15, quad = lane >> 4;
  int qt = w >> 2, kh = w & 3;
  int b = blockIdx.x >> 5;
  int n0 = (blockIdx.x & 31) * 32;
  long gbase = (long)b * NN;
  const unsigned short* vrow = vtb + (long)b*HID*NN;

  s8v aq = *(const s8v*)(qb + (gbase + n0 + qt*16 + col)*DKK + quad*8);

  f4v acc[4];
#pragma unroll
  for (int t = 0; t < 4; ++t) acc[t] = (f4v){0.f,0.f,0.f,0.f};
  float psum[4] = {0.f,0.f,0.f,0.f};
  const float rs = 0.17677669529663687f;
  const int cbeg = kh * 256;

#pragma unroll 2
  for (int it = 0; it < 4; ++it) {
    int c0 = cbeg + it*64;
    int pb = it & 1;
    f4v s4[4];
#pragma unroll
    for (int nt = 0; nt < 4; ++nt) {
      s8v bk = *(const s8v*)(kb + (gbase + c0 + nt*16 + col)*DKK + quad*8);
      s4[nt] = __builtin_amdgcn_mfma_f32_16x16x32_bf16(aq, bk,
                (f4v){0.f,0.f,0.f,0.f}, 0, 0, 0);
    }
#pragma unroll
    for (int r = 0; r < 4; ++r) {
      float p0 = expf(s4[0][r]*rs), p1 = expf(s4[1][r]*rs);
      float p2 = expf(s4[2][r]*rs), p3 = expf(s4[3][r]*rs);
      psum[r] += (p0 + p1) + (p2 + p3);
      int row = quad*4 + r;
      pl[pb][w][row][col]      = f2b(p0);
      pl[pb][w][row][16 + col] = f2b(p1);
      pl[pb][w][row][32 + col] = f2b(p2);
      pl[pb][w][row][48 + col] = f2b(p3);
    }
#pragma unroll
    for (int ks = 0; ks < 2; ++ks) {
      s8v ap = *(const s8v*)&pl[pb][w][col][ks*32 + quad*8];
#pragma unroll
      for (int nt = 0; nt < 4; ++nt) {
        s8v bv = *(const s8v*)(vrow + (long)(nt*16 + col)*NN + c0 + ks*32 + quad*8);
        acc[nt] = __builtin_amdgcn_mfma_f32_16x16x32_bf16(ap, bv, acc[nt], 0, 0, 0);
      }
    }
  }

#pragma unroll
  for (int r = 0; r < 4; ++r) {
    float v = psum[r];
#pragma unroll
    for (int off = 1; off < 16; off <<= 1) v += __shfl_xor(v, off);
    psum[r] = v;
  }
#pragma unroll
  for (int t = 0; t < 4; ++t)
#pragma unroll
    for (int r = 0; r < 4; ++r)
      accb[w][quad*4 + r][t*16 + col] = acc[t][r];
  if (col == 0) {
#pragma unroll
    for (int r = 0; r < 4; ++r) lb[w][quad*4 + r] = psum[r];
  }
  __syncthreads();

  int f = *flag;
#pragma unroll
  for (int rr = 0; rr < 4; ++rr) {
    int rl = w*4 + rr;                 // 0..31
    int qtt = rl >> 4, lrr = rl & 15;
    float a = accb[4*qtt][lrr][lane] + accb[4*qtt + 1][lrr][lane]
            + accb[4*qtt + 2][lrr][lane] + accb[4*qtt + 3][lrr][lane];
    float l = lb[4*qtt][lrr] + lb[4*qtt + 1][lrr]
            + lb[4*qtt + 2][lrr] + lb[4*qtt + 3][lrr];
    float val = a / l;
    long idx = (gbase + n0 + rl)*HID + lane;
    if (f) ((float*)outp)[idx] = val;
    else   ((bf16*)outp)[idx] = __float2bfloat16(val);
  }
}

// ================================================================ launch
extern "C" void kernel_launch(void* const* d_in, const int* in_sizes, int n_in,
                              void* d_out, int out_size, void* d_ws, size_t ws_size,
                              hipStream_t stream) {
  static const int EXP[30] = {
    49152, 49152, 384, 128, 49152, 768, 16384, 256,
    524288, 8192, 524288, 256, 256, 256, 256, 256,
    8192, 8192, 16384, 524288, 8192, 524288, 256, 256,
    256, 256, 256, 4096, 4096, 8192
  };
  // z[2] + enc + qb + kb + vt + wcw  (floats)
  const size_t NEED = (size_t)(2*ZS + 524288 + 524288 + 524288 + 1048576 + 1048576) * 4 + 64;
  bool ok = (n_in == 30) && (ws_size >= NEED) && (out_size == BB*NN*HID);
  if (ok) for (int i = 0; i < 30; ++i) ok = ok && (in_sizes[i] == EXP[i]);
  if (!ok) {
    k_zero<<<(BB*NN*HID + 255)/256, 256, 0, stream>>>((unsigned short*)d_out, BB*NN*HID);
    return;
  }

  float* z   = (float*)d_ws;             // 2 × [4,1024,4,64]
  float* enc = z   + 2*ZS;               // [4,1024,128]
  float* qb  = enc + 524288;             // bf16 q [32 groups][1024][32]
  float* kb  = qb  + 524288;             // bf16 k
  float* vb  = kb  + 1048576 - 524288 + 524288;  // bf16 V^T [32 groups][64][1024]
  vb = kb + 524288;
  float* wcf = vb  + 1048576;            // bf16 FF weights [4 si][4][131072]
  int*  flag = (int*)(wcf + 1048576);
  unsigned short* wcw = (unsigned short*)wcf;

  const void *i_traffic=d_in[0], *i_user=d_in[1], *i_pw=d_in[2], *i_pb=d_in[3],
    *i_mw=d_in[4], *i_mb=d_in[5], *i_ow=d_in[6], *i_ob=d_in[7], *i_f1w=d_in[8],
    *i_f1b=d_in[9], *i_f2w=d_in[10], *i_f2b=d_in[11], *i_l1g=d_in[12],
    *i_l1b=d_in[13], *i_l2g=d_in[14], *i_l2b=d_in[15], *i_gwq=d_in[16],
    *i_gwk=d_in[17], *i_gwv=d_in[18], *i_gf1w=d_in[19], *i_gf1b=d_in[20],
    *i_gf2w=d_in[21], *i_gf2b=d_in[22], *i_gl1g=d_in[23], *i_gl1b=d_in[24],
    *i_gl2g=d_in[25], *i_gl2b=d_in[26], *i_cwq=d_in[27], *i_cwk=d_in[28],
    *i_cwv=d_in[29];

  // all 16 FF weight matrices + in-kernel dtype detect, one dispatch
  k_wconv<<<1024, 256, 0, stream>>>(i_f1w, i_f2w, i_gf1w, i_gf2w, wcw,
      i_traffic, flag);

  // layer 0: patch -> tattn -> FF -> gqkv, then graph attention
  k_tff<<<512, 256, 0, stream>>>(z,
      i_traffic, i_user, i_pw, i_pb,
      i_mw, i_mb, i_ow, i_ob,
      i_l1g, i_l1b, wcw, 0, i_f1b, i_f2b, i_l2g, i_l2b,
      i_gf1b, i_gf2b, i_gl2g, i_gl2b,
      i_gwq, i_gwk, i_gwv,
      (unsigned short*)qb, (unsigned short*)kb, (unsigned short*)vb, flag);
  k_gattn<<<1024, 512, 0, stream>>>(z,
      (const unsigned short*)qb, (const unsigned short*)kb,
      (const unsigned short*)vb, i_gl1g, i_gl1b, 0, flag);
  // layer 1: gaFF(layer0) -> tattn -> FF -> gqkv, then graph attention
  k_tff<<<512, 256, 0, stream>>>(z,
      i_traffic, i_user, i_pw, i_pb,
      i_mw, i_mb, i_ow, i_ob,
      i_l1g, i_l1b, wcw, 1, i_f1b, i_f2b, i_l2g, i_l2b,
      i_gf1b, i_gf2b, i_gl2g, i_gl2b,
      i_gwq, i_gwk, i_gwv,
      (unsigned short*)qb, (unsigned short*)kb, (unsigned short*)vb, flag);
  k_gattn<<<1024, 512, 0, stream>>>(z,
      (const unsigned short*)qb, (const unsigned short*)kb,
      (const unsigned short*)vb, i_gl1g, i_gl1b, 1, flag);
  // final ga-FF (layer 1) + fused segment-pool
  k_ffmfma<<<512, 256, 0, stream>>>(z, wcw, 1, 2,
      i_gf1b, i_gf2b, i_gl2g, i_gl2b, enc, 1, flag);

  k_fqkv<<<BB*NN, 128, 0, stream>>>(enc, i_cwq, i_cwk, i_cwv,
      (unsigned short*)qb, (unsigned short*)kb, (unsigned short*)vb, flag);
  k_fattn<<<BB*32, 512, 0, stream>>>((const unsigned short*)qb,
      (const unsigned short*)kb, (unsigned short*)vb, d_out, flag);
}